// Round 9
// baseline (1300.239 us; speedup 1.0000x reference)
//
#include <hip/hip_runtime.h>
#include <hip/hip_fp16.h>
#include <cstdint>

#define N_VOX   200000
#define N_PAIRS 100000
#define KK      27
#define INC     64
#define OUTC    64
#define BN_EPS  1e-5f

// Output partitioning: 64 rows/part, exact tiling (3125*64 = 200000)
#define RPP       64
#define NPART     3125
#define NBIN      (KK * NPART)         // 84375
#define BIN_CAP   64                   // per-bin: avg 32, +5.7 sigma
#define T_CAP     1056                 // per-block slots: avg 864, +6.5 sigma
#define OVF_CAP   4096
#define YSTRIDE   68                   // yloc row stride (floats)

typedef __attribute__((ext_vector_type(8))) short bf16x8;
typedef __attribute__((ext_vector_type(4))) float f32x4;

__device__ inline uint32_t cvt_pk_bf16(float lo, float hi) {
    uint32_t r;
    asm("v_cvt_pk_bf16_f32 %0, %1, %2" : "=v"(r) : "v"(lo), "v"(hi));
    return r;
}

__device__ inline bf16x8 pack_frag(float a, float b, float c, float d,
                                   float e, float f, float g, float h) {
    union { uint32_t u[4]; bf16x8 v; } cv;
    cv.u[0] = cvt_pk_bf16(a, b);
    cv.u[1] = cvt_pk_bf16(c, d);
    cv.u[2] = cvt_pk_bf16(e, f);
    cv.u[3] = cvt_pk_bf16(g, h);
    return cv.v;
}

__device__ inline bf16x8 as_frag(uint4 u) {
    union { uint4 u; bf16x8 v; } cv; cv.u = u; return cv.v;
}

__device__ inline void pk_atomic(__half2* addr, float lo, float hi) {
    __half2 h = __floats2half2_rn(lo, hi);
    uint32_t u; __builtin_memcpy(&u, &h, 4);
    asm volatile("global_atomic_pk_add_f16 %0, %1, off" : : "v"(addr), "v"(u) : "memory");
}

// ---------------------------------------------------------------------------
// Pre-pack w into bf16 B-fragment layout (proven): fid=(k*4+n)*2+kk, lane l
// holds B[kbase + (l>>4)*8 + j][n*16 + (l&15)], uint4 at wp[fid*64 + l].
// ---------------------------------------------------------------------------
__global__ __launch_bounds__(256) void pack_w(
    const float* __restrict__ w, uint4* __restrict__ wp)
{
    const int tid = blockIdx.x * blockDim.x + threadIdx.x;
    if (tid >= KK * 8 * 64) return;
    const int lane = tid & 63;
    const int fid  = tid >> 6;
    const int k    = fid >> 3;
    const int n    = (fid & 7) >> 1;
    const int kk   = fid & 1;
    const int row  = lane & 15;
    const int kg   = lane >> 4;
    const int kbase = kk * 32 + kg * 8;

    const float* bp = w + (size_t)k * (INC * OUTC) + (size_t)kbase * OUTC + n * 16 + row;
    bf16x8 f = pack_frag(bp[0*OUTC], bp[1*OUTC], bp[2*OUTC], bp[3*OUTC],
                         bp[4*OUTC], bp[5*OUTC], bp[6*OUTC], bp[7*OUTC]);
    union { bf16x8 v; uint4 u; } cv; cv.v = f;
    wp[(size_t)fid * 64 + lane] = cv.u;
}

// ---------------------------------------------------------------------------
// Bin by (k, OUTPUT partition of 64 rows). Record = in (18b) | local_out<<18 (6b).
// ---------------------------------------------------------------------------
__global__ __launch_bounds__(256) void scatter_pairs(
    const int* __restrict__ kin, const int* __restrict__ kout,
    uint32_t* __restrict__ cnt, uint32_t* __restrict__ bins,
    uint32_t* __restrict__ ovf_cnt, uint32_t* __restrict__ ovf)
{
    const int k = blockIdx.y;
    const int i = blockIdx.x * blockDim.x + threadIdx.x;
    if (i >= N_PAIRS) return;
    const int idx = k * N_PAIRS + i;
    const int out = kout[idx];
    const int in  = kin[idx];
    const int part  = out >> 6;
    const int local = out & 63;
    const int bin   = k * NPART + part;
    const uint32_t pos = atomicAdd(&cnt[bin], 1u);
    if (pos < BIN_CAP) {
        bins[(size_t)bin * BIN_CAP + pos] = (uint32_t)in | ((uint32_t)local << 18);
    } else {
        const uint32_t p2 = atomicAdd(ovf_cnt, 1u);
        if (p2 < OVF_CAP) ovf[p2] = (uint32_t)idx;
    }
}

// ---------------------------------------------------------------------------
// Staged conv: block (512 thr, 8 waves) = one 64-row output partition.
//   Phase 0: copy this block's bin records into LDS recs[] (+ prefix).
//   Phase 1: STAGING — gather x rows for all T records into LDS xstage as
//            bf16, 16 lanes per record (256B coalesced), f32->bf16 in flight.
//            Near-zero register pressure -> deep MLP.
//   Phase 2: MFMA from LDS operands only; scatter via ds_add into yloc.
//   Phase 3: coalesced store-flush. No global atomics anywhere.
// ---------------------------------------------------------------------------
__global__ __launch_bounds__(512) void conv_staged(
    const float* __restrict__ x, const uint4* __restrict__ wp,
    const uint32_t* __restrict__ cnt, const uint32_t* __restrict__ bins,
    float* __restrict__ y)
{
    __shared__ __align__(16) uint32_t xstage[T_CAP * 32];     // 135168 B
    __shared__ __align__(16) float    yloc[RPP * YSTRIDE];    // 17408 B
    __shared__ uint32_t recs[T_CAP + 16];                     // 4288 B (+pad for quad reads)
    __shared__ int sh_pre[KK + 1];

    const int tid  = threadIdx.x;
    const int lane = tid & 63;
    const int wid  = tid >> 6;            // 0..7
    const int row  = lane & 15;
    const int kg   = lane >> 4;
    const int part = blockIdx.x;

    // zero yloc + recs pad
    for (int i = tid; i < RPP * YSTRIDE; i += 512) yloc[i] = 0.f;
    if (tid < 16) recs[T_CAP + tid] = 0u;
    __syncthreads();
    if (tid == 0) {
        int s = 0;
        for (int i = 0; i < KK; ++i) {
            sh_pre[i] = s;
            int c = (int)cnt[i * NPART + part];
            if (c > BIN_CAP) c = BIN_CAP;
            s += c;
            if (s > T_CAP) s = T_CAP;     // ~1e-11 truncation guard
        }
        sh_pre[KK] = s;
    }
    __syncthreads();
    const int T = sh_pre[KK];

    // Phase 0: copy records to LDS (flat over slots, scan for k)
    for (int f = tid; f < T; f += 512) {
        int k = 0;
        #pragma unroll
        for (int i = 1; i < KK; ++i) k += (f >= sh_pre[i]) ? 1 : 0;
        const int pos = f - sh_pre[k];
        recs[f] = bins[(size_t)(k * NPART + part) * BIN_CAP + pos];
    }
    __syncthreads();

    // Phase 1: staging gather. 16 lanes per record; wave does 4 records/iter.
    for (int f0 = wid * 4; f0 < T; f0 += 32) {
        const int f = f0 + kg;             // kg selects record within the 4
        if (f < T) {
            const int in = (int)(recs[f] & 0x3FFFFu);
            const float4 v = *(const float4*)(x + (size_t)in * INC + row * 4);
            uint32_t* dst = &xstage[f * 32 + row * 2];
            dst[0] = cvt_pk_bf16(v.x, v.y);
            dst[1] = cvt_pk_bf16(v.z, v.w);
        }
    }
    __syncthreads();

    // Phase 2: MFMA from LDS; ds_add scatter into yloc.
    for (int k = wid; k < KK; k += 8) {
        const int p0   = sh_pre[k];
        const int cntk = sh_pre[k + 1] - p0;
        if (cntk == 0) continue;
        const int nch = (cntk + 15) >> 4;

        const size_t fb = (size_t)(k * 8) * 64 + lane;
        const uint4 b0 = wp[fb];        const uint4 b1 = wp[fb + 64];
        const uint4 b2 = wp[fb + 128];  const uint4 b3 = wp[fb + 192];
        const uint4 b4 = wp[fb + 256];  const uint4 b5 = wp[fb + 320];
        const uint4 b6 = wp[fb + 384];  const uint4 b7 = wp[fb + 448];

        for (int ch = 0; ch < nch; ++ch) {
            const int e0 = ch * 16;
            const int count = cntk - e0;

            // A-row slot for my lane (clamped; masked by count below)
            const int sl = min(p0 + e0 + row, T_CAP - 1);
            const uint32_t* xp = &xstage[sl * 32 + kg * 4];
            const bf16x8 a0 = as_frag(*(const uint4*)(xp));
            const bf16x8 a1 = as_frag(*(const uint4*)(xp + 16));

            // scatter records for my kg group (pad-safe quad read)
            const uint4 ro = *(const uint4*)&recs[p0 + e0 + kg * 4];

            f32x4 c0 = {0,0,0,0}, c1 = {0,0,0,0}, c2 = {0,0,0,0}, c3 = {0,0,0,0};
            c0 = __builtin_amdgcn_mfma_f32_16x16x32_bf16(a0, as_frag(b0), c0, 0, 0, 0);
            c0 = __builtin_amdgcn_mfma_f32_16x16x32_bf16(a1, as_frag(b1), c0, 0, 0, 0);
            c1 = __builtin_amdgcn_mfma_f32_16x16x32_bf16(a0, as_frag(b2), c1, 0, 0, 0);
            c1 = __builtin_amdgcn_mfma_f32_16x16x32_bf16(a1, as_frag(b3), c1, 0, 0, 0);
            c2 = __builtin_amdgcn_mfma_f32_16x16x32_bf16(a0, as_frag(b4), c2, 0, 0, 0);
            c2 = __builtin_amdgcn_mfma_f32_16x16x32_bf16(a1, as_frag(b5), c2, 0, 0, 0);
            c3 = __builtin_amdgcn_mfma_f32_16x16x32_bf16(a0, as_frag(b6), c3, 0, 0, 0);
            c3 = __builtin_amdgcn_mfma_f32_16x16x32_bf16(a1, as_frag(b7), c3, 0, 0, 0);

            const uint32_t r0 = ro.x, r1 = ro.y, r2 = ro.z, r3 = ro.w;
            #pragma unroll
            for (int j = 0; j < 4; ++j) {
                const uint32_t rj = (j == 0) ? r0 : (j == 1) ? r1 : (j == 2) ? r2 : r3;
                if (kg * 4 + j < count) {
                    const int local = (int)((rj >> 18) & 63u);
                    float* lb = &yloc[local * YSTRIDE + row];
                    __hip_atomic_fetch_add(lb + 0,  c0[j], __ATOMIC_RELAXED, __HIP_MEMORY_SCOPE_WORKGROUP);
                    __hip_atomic_fetch_add(lb + 16, c1[j], __ATOMIC_RELAXED, __HIP_MEMORY_SCOPE_WORKGROUP);
                    __hip_atomic_fetch_add(lb + 32, c2[j], __ATOMIC_RELAXED, __HIP_MEMORY_SCOPE_WORKGROUP);
                    __hip_atomic_fetch_add(lb + 48, c3[j], __ATOMIC_RELAXED, __HIP_MEMORY_SCOPE_WORKGROUP);
                }
            }
        }
    }

    __syncthreads();
    // Phase 3: flush 64 rows (exact tiling, no bounds check needed)
    float4* yg = (float4*)(y + (size_t)part * RPP * OUTC);
    #pragma unroll
    for (int i = 0; i < 2; ++i) {
        const int i4 = tid + i * 512;              // 0..1023
        const int r  = i4 >> 4;
        const int c4 = i4 & 15;
        yg[i4] = *(const float4*)(yloc + r * YSTRIDE + c4 * 4);
    }
}

// ---------------------------------------------------------------------------
// Overflow fixup (expected ~0 entries), f32 atomics, after flush.
// ---------------------------------------------------------------------------
__global__ __launch_bounds__(64) void ovf_fix(
    const float* __restrict__ x, const float* __restrict__ w,
    const int* __restrict__ kin, const int* __restrict__ kout,
    const uint32_t* __restrict__ ovf_cnt, const uint32_t* __restrict__ ovf,
    float* __restrict__ y)
{
    const int t = threadIdx.x;                 // 64 threads, t = channel
    const int n = (int)min(*ovf_cnt, (uint32_t)OVF_CAP);
    for (int i = blockIdx.x; i < n; i += gridDim.x) {
        const int idx = (int)ovf[i];
        const int k   = idx / N_PAIRS;
        const int in  = kin[idx];
        const int out = kout[idx];
        float acc = 0.f;
        for (int d = 0; d < INC; ++d)
            acc = fmaf(x[(size_t)in * INC + d], w[(size_t)k * INC * OUTC + d * OUTC + t], acc);
        unsafeAtomicAdd(&y[(size_t)out * OUTC + t], acc);
    }
}

// ---------------------------------------------------------------------------
// BN stats / finalize / apply (f32, y in d_out) — proven
// ---------------------------------------------------------------------------
__global__ __launch_bounds__(256) void bn_reduce(
    const float* __restrict__ y, float* __restrict__ stats)
{
    __shared__ float s_sum[256];
    __shared__ float s_sq[256];

    const int c = threadIdx.x & 63;
    const int row0 = (blockIdx.x * blockDim.x + threadIdx.x) >> 6;
    const int rstride = (gridDim.x * blockDim.x) >> 6;

    float s = 0.f, ss = 0.f;
    for (int r = row0; r < N_VOX; r += rstride) {
        const float v = y[(size_t)r * OUTC + c];
        s += v;
        ss += v * v;
    }
    s_sum[threadIdx.x] = s;
    s_sq[threadIdx.x]  = ss;
    __syncthreads();

    if (threadIdx.x < 64) {
        const float ts  = (s_sum[c] + s_sum[64 + c]) + (s_sum[128 + c] + s_sum[192 + c]);
        const float tss = (s_sq[c]  + s_sq[64 + c])  + (s_sq[128 + c]  + s_sq[192 + c]);
        atomicAdd(&stats[c], ts);
        atomicAdd(&stats[64 + c], tss);
    }
}

__global__ void bn_finalize(
    const float* __restrict__ stats, const float* __restrict__ gamma,
    const float* __restrict__ beta, float* __restrict__ coef)
{
    const int c = threadIdx.x;
    if (c < 64) {
        const float inv_n = 1.0f / (float)N_VOX;
        const float mean  = stats[c] * inv_n;
        const float var   = stats[64 + c] * inv_n - mean * mean;
        const float scale = gamma[c] * rsqrtf(var + BN_EPS);
        coef[c]      = scale;
        coef[64 + c] = beta[c] - mean * scale;
    }
}

__global__ __launch_bounds__(256) void bn_apply(
    float* __restrict__ y, const float* __restrict__ coef)
{
    const size_t total4 = (size_t)N_VOX * OUTC / 4;
    size_t i = (size_t)blockIdx.x * blockDim.x + threadIdx.x;
    const size_t stride = (size_t)gridDim.x * blockDim.x;

    const int c0 = (int)((i * 4) & 63);
    const float sc0 = coef[c0 + 0], sh0 = coef[64 + c0 + 0];
    const float sc1 = coef[c0 + 1], sh1 = coef[64 + c0 + 1];
    const float sc2 = coef[c0 + 2], sh2 = coef[64 + c0 + 2];
    const float sc3 = coef[c0 + 3], sh3 = coef[64 + c0 + 3];

    float4* y4 = (float4*)y;
    for (; i < total4; i += stride) {
        float4 v = y4[i];
        v.x = fmaxf(0.f, fmaf(v.x, sc0, sh0));
        v.y = fmaxf(0.f, fmaf(v.y, sc1, sh1));
        v.z = fmaxf(0.f, fmaf(v.z, sc2, sh2));
        v.w = fmaxf(0.f, fmaf(v.w, sc3, sh3));
        y4[i] = v;
    }
}

// ==================== fallback tier: unbinned fp16 pk-atomic path ==========
__global__ __launch_bounds__(256) void conv_mfma16(
    const float* __restrict__ x, const float* __restrict__ w,
    const int* __restrict__ kin, const int* __restrict__ kout,
    __half2* __restrict__ y2)
{
    const int lane = threadIdx.x & 63;
    const int wid  = threadIdx.x >> 6;
    const int k    = blockIdx.y;
    const int row  = lane & 15;
    const int kg   = lane >> 4;

    const float* wk = w + (size_t)k * (INC * OUTC);

    bf16x8 bfrag[4][2];
    #pragma unroll
    for (int n = 0; n < 4; ++n) {
        #pragma unroll
        for (int kk = 0; kk < 2; ++kk) {
            const int kbase = kk * 32 + kg * 8;
            const float* bp = wk + (size_t)kbase * OUTC + n * 16 + row;
            bfrag[n][kk] = pack_frag(bp[0*OUTC], bp[1*OUTC], bp[2*OUTC], bp[3*OUTC],
                                     bp[4*OUTC], bp[5*OUTC], bp[6*OUTC], bp[7*OUTC]);
        }
    }

    const int* kin_k  = kin  + (size_t)k * N_PAIRS;
    const int* kout_k = kout + (size_t)k * N_PAIRS;

    const int NCHUNK = N_PAIRS / 16;
    const int nwaves = gridDim.x * 4;

    for (int ch = blockIdx.x * 4 + wid; ch < NCHUNK; ch += nwaves) {
        const int e0 = ch * 16;
        const int in_idx = kin_k[e0 + row];
        const int4 oi = *(const int4*)(kout_k + e0 + kg * 4);

        const float* xr = x + (size_t)in_idx * INC + kg * 8;
        bf16x8 afrag[2];
        #pragma unroll
        for (int kk = 0; kk < 2; ++kk) {
            const f32x4 a0 = *(const f32x4*)(xr + kk * 32);
            const f32x4 a1 = *(const f32x4*)(xr + kk * 32 + 4);
            afrag[kk] = pack_frag(a0.x, a0.y, a0.z, a0.w, a1.x, a1.y, a1.z, a1.w);
        }

        f32x4 acc[4] = {{0,0,0,0},{0,0,0,0},{0,0,0,0},{0,0,0,0}};
        #pragma unroll
        for (int n = 0; n < 4; ++n) {
            acc[n] = __builtin_amdgcn_mfma_f32_16x16x32_bf16(afrag[0], bfrag[n][0], acc[n], 0, 0, 0);
            acc[n] = __builtin_amdgcn_mfma_f32_16x16x32_bf16(afrag[1], bfrag[n][1], acc[n], 0, 0, 0);
        }

        const int orow[4] = {oi.x, oi.y, oi.z, oi.w};
        #pragma unroll
        for (int j = 0; j < 4; ++j) {
            __half2* rbase = y2 + (size_t)orow[j] * (OUTC/2) + (row >> 1);
            #pragma unroll
            for (int n = 0; n < 4; ++n) {
                const float v = acc[n][j];
                const float p = __shfl_xor(v, 1);
                if (!(lane & 1)) pk_atomic(rbase + n * 8, v, p);
            }
        }
    }
}

__global__ __launch_bounds__(256) void bn_reduce16(
    const __half2* __restrict__ y2, float* __restrict__ stats)
{
    __shared__ float s0a[256], s1a[256], q0a[256], q1a[256];

    const int c2 = threadIdx.x & 31;
    const int row0 = (blockIdx.x * blockDim.x + threadIdx.x) >> 5;
    const int rstride = (gridDim.x * blockDim.x) >> 5;

    float s0 = 0.f, s1 = 0.f, q0 = 0.f, q1 = 0.f;
    for (int r = row0; r < N_VOX; r += rstride) {
        const float2 v = __half22float2(y2[(size_t)r * 32 + c2]);
        s0 += v.x; q0 += v.x * v.x;
        s1 += v.y; q1 += v.y * v.y;
    }
    s0a[threadIdx.x] = s0; s1a[threadIdx.x] = s1;
    q0a[threadIdx.x] = q0; q1a[threadIdx.x] = q1;
    __syncthreads();

    if (threadIdx.x < 64) {
        const int c = threadIdx.x, p = c >> 1, b = c & 1;
        float ts = 0.f, tq = 0.f;
        #pragma unroll
        for (int g = 0; g < 8; ++g) {
            ts += b ? s1a[g * 32 + p] : s0a[g * 32 + p];
            tq += b ? q1a[g * 32 + p] : q0a[g * 32 + p];
        }
        atomicAdd(&stats[c], ts);
        atomicAdd(&stats[64 + c], tq);
    }
}

__global__ __launch_bounds__(256) void bn_apply16(
    const __half2* __restrict__ y2, const float* __restrict__ coef,
    float2* __restrict__ out2)
{
    const size_t total2 = (size_t)N_VOX * 32;
    size_t i = (size_t)blockIdx.x * blockDim.x + threadIdx.x;
    const size_t stride = (size_t)gridDim.x * blockDim.x;

    const int c2 = (int)(i & 31);
    const float sc0 = coef[2*c2], sh0 = coef[64 + 2*c2];
    const float sc1 = coef[2*c2 + 1], sh1 = coef[64 + 2*c2 + 1];

    for (; i < total2; i += stride) {
        const float2 v = __half22float2(y2[i]);
        float2 o;
        o.x = fmaxf(0.f, fmaf(v.x, sc0, sh0));
        o.y = fmaxf(0.f, fmaf(v.y, sc1, sh1));
        out2[i] = o;
    }
}

extern "C" void kernel_launch(void* const* d_in, const int* in_sizes, int n_in,
                              void* d_out, int out_size, void* d_ws, size_t ws_size,
                              hipStream_t stream)
{
    const float* x     = (const float*)d_in[0];
    const float* w     = (const float*)d_in[1];
    const float* gamma = (const float*)d_in[2];
    const float* beta  = (const float*)d_in[3];
    const int*   kin   = (const int*)d_in[4];
    const int*   kout  = (const int*)d_in[5];

    float* y = (float*)d_out;

    // Tier A ws layout (bytes)
    const size_t off_cnt   = 0;                                   // 84375 u32 -> 337,920 (padded)
    const size_t off_ovfc  = 337920;                              // 64
    const size_t off_ovf   = 337984;                              // 16,384
    const size_t off_stats = 354368;                              // 512
    const size_t off_coef  = 354880;                              // 512
    const size_t off_wp    = 355392;                              // 221,184
    const size_t off_bins  = 576576;                              // 21,600,000
    const size_t needA     = off_bins + (size_t)NBIN * BIN_CAP * 4;   // ~22.2 MB

    const size_t y16_bytes = (size_t)N_VOX * OUTC * sizeof(__half);   // 25.6 MB
    const size_t needB = y16_bytes + 1024;

    if (ws_size >= needA) {
        uint32_t* cnt     = (uint32_t*)((char*)d_ws + off_cnt);
        uint32_t* ovfc    = (uint32_t*)((char*)d_ws + off_ovfc);
        uint32_t* ovf     = (uint32_t*)((char*)d_ws + off_ovf);
        float*    stats   = (float*)((char*)d_ws + off_stats);
        float*    coef    = (float*)((char*)d_ws + off_coef);
        uint4*    wp      = (uint4*)((char*)d_ws + off_wp);
        uint32_t* bins    = (uint32_t*)((char*)d_ws + off_bins);

        // zero cnt + ovf + stats (bins guarded by cnt; y store-flushed)
        hipMemsetAsync(d_ws, 0, off_coef + 512, stream);

        pack_w<<<54, 256, 0, stream>>>(w, wp);
        scatter_pairs<<<dim3((N_PAIRS + 255) / 256, KK), 256, 0, stream>>>(
            kin, kout, cnt, bins, ovfc, ovf);
        conv_staged<<<NPART, 512, 0, stream>>>(x, wp, cnt, bins, y);
        ovf_fix<<<128, 64, 0, stream>>>(x, w, kin, kout, ovfc, ovf, y);
        bn_reduce<<<512, 256, 0, stream>>>(y, stats);
        bn_finalize<<<1, 64, 0, stream>>>(stats, gamma, beta, coef);
        bn_apply<<<2048, 256, 0, stream>>>(y, coef);
    } else if (ws_size >= needB) {
        // unbinned fp16 packed-atomic path (proven 556 us conv)
        __half2* y2   = (__half2*)d_ws;
        float* stats  = (float*)((char*)d_ws + y16_bytes);
        float* coef   = stats + 128;

        hipMemsetAsync(y2, 0, y16_bytes, stream);
        hipMemsetAsync(stats, 0, 128 * sizeof(float), stream);

        conv_mfma16<<<dim3(64, KK), 256, 0, stream>>>(x, w, kin, kout, y2);
        bn_reduce16<<<512, 256, 0, stream>>>(y2, stats);
        bn_finalize<<<1, 64, 0, stream>>>(stats, gamma, beta, coef);
        bn_apply16<<<2048, 256, 0, stream>>>(y2, coef, (float2*)d_out);
    }
}

// Round 10
// 555.997 us; speedup vs baseline: 2.3386x; 2.3386x over previous
//
#include <hip/hip_runtime.h>
#include <cstdint>

#define N_VOX   200000
#define N_PAIRS 100000
#define KK      27
#define INC     64
#define OUTC    64
#define BN_EPS  1e-5f

// Fixed-point packing: 4 channels x 16-bit biased fixed-point per u64.
// scale 512 (res ~2e-3), bias 0x8000 per field. Band: field stays in
// [2^15 - 2^14, 2^15 + 2^14] since sum(|contrib|) << 32 per channel.
#define QS   512.0f
#define QINV (1.0f / 512.0f)

typedef __attribute__((ext_vector_type(8))) short bf16x8;
typedef __attribute__((ext_vector_type(4))) float f32x4;

__device__ inline uint32_t cvt_pk_bf16(float lo, float hi) {
    uint32_t r;
    asm("v_cvt_pk_bf16_f32 %0, %1, %2" : "=v"(r) : "v"(lo), "v"(hi));
    return r;
}

__device__ inline bf16x8 pack_frag(float a, float b, float c, float d,
                                   float e, float f, float g, float h) {
    union { uint32_t u[4]; bf16x8 v; } cv;
    cv.u[0] = cvt_pk_bf16(a, b);
    cv.u[1] = cvt_pk_bf16(c, d);
    cv.u[2] = cvt_pk_bf16(e, f);
    cv.u[3] = cvt_pk_bf16(g, h);
    return cv.v;
}

// ---------------------------------------------------------------------------
// init: every 16-bit field = 0x8000 (bias), i.e. value 0.
// ---------------------------------------------------------------------------
__global__ __launch_bounds__(256) void init_q(unsigned long long* __restrict__ yq)
{
    const size_t total = (size_t)N_VOX * 16;          // u64 slots
    size_t i = (size_t)blockIdx.x * blockDim.x + threadIdx.x;
    const size_t stride = (size_t)gridDim.x * blockDim.x;
    for (; i < total; i += stride) yq[i] = 0x8000800080008000ULL;
}

// ---------------------------------------------------------------------------
// MFMA conv (r3-proven shape) + packed-u64 integer atomic scatter.
// One wave per 16-pair chunk; blockIdx.y = k. Lane l: A-row = l&15 = row,
// k-group kg = l>>4. D: lane l reg j -> row=kg*4+j (pair), col=n*16+row.
// Scatter: quad-lane groups pack 4 consecutive channels into one u64
// fixed-point delta with carry compensation; one atomicAdd per 4 channels.
// ---------------------------------------------------------------------------
__global__ __launch_bounds__(256) void conv_q(
    const float* __restrict__ x, const float* __restrict__ w,
    const int* __restrict__ kin, const int* __restrict__ kout,
    unsigned long long* __restrict__ yq)
{
    const int lane = threadIdx.x & 63;
    const int wid  = threadIdx.x >> 6;
    const int k    = blockIdx.y;
    const int row  = lane & 15;
    const int kg   = lane >> 4;

    const float* wk = w + (size_t)k * (INC * OUTC);

    bf16x8 bfrag[4][2];
    #pragma unroll
    for (int n = 0; n < 4; ++n) {
        #pragma unroll
        for (int kk = 0; kk < 2; ++kk) {
            const int kbase = kk * 32 + kg * 8;
            const float* bp = wk + (size_t)kbase * OUTC + n * 16 + row;
            bfrag[n][kk] = pack_frag(bp[0*OUTC], bp[1*OUTC], bp[2*OUTC], bp[3*OUTC],
                                     bp[4*OUTC], bp[5*OUTC], bp[6*OUTC], bp[7*OUTC]);
        }
    }

    const int* kin_k  = kin  + (size_t)k * N_PAIRS;
    const int* kout_k = kout + (size_t)k * N_PAIRS;

    const int NCHUNK = N_PAIRS / 16;       // 6250, exact
    const int nwaves = gridDim.x * 4;

    for (int ch = blockIdx.x * 4 + wid; ch < NCHUNK; ch += nwaves) {
        const int e0 = ch * 16;
        const int in_idx = kin_k[e0 + row];
        const int4 oi = *(const int4*)(kout_k + e0 + kg * 4);

        const float* xr = x + (size_t)in_idx * INC + kg * 8;
        bf16x8 afrag[2];
        #pragma unroll
        for (int kk = 0; kk < 2; ++kk) {
            const f32x4 a0 = *(const f32x4*)(xr + kk * 32);
            const f32x4 a1 = *(const f32x4*)(xr + kk * 32 + 4);
            afrag[kk] = pack_frag(a0.x, a0.y, a0.z, a0.w, a1.x, a1.y, a1.z, a1.w);
        }

        f32x4 acc[4] = {{0,0,0,0},{0,0,0,0},{0,0,0,0},{0,0,0,0}};
        #pragma unroll
        for (int n = 0; n < 4; ++n) {
            acc[n] = __builtin_amdgcn_mfma_f32_16x16x32_bf16(afrag[0], bfrag[n][0], acc[n], 0, 0, 0);
            acc[n] = __builtin_amdgcn_mfma_f32_16x16x32_bf16(afrag[1], bfrag[n][1], acc[n], 0, 0, 0);
        }

        const int orow[4] = {oi.x, oi.y, oi.z, oi.w};
        #pragma unroll
        for (int j = 0; j < 4; ++j) {
            unsigned long long* rbase = yq + (size_t)orow[j] * 16 + (row >> 2);
            #pragma unroll
            for (int n = 0; n < 4; ++n) {
                // quantize my channel's contribution
                const float v = fminf(fmaxf(acc[n][j], -31.f), 31.f);
                const int d = __float2int_rn(v * QS);
                // gather quad (4 consecutive channels) onto lane (l&3)==0
                const int dx = __shfl_xor(d, 1);
                uint32_t pr = ((uint32_t)(uint16_t)d) | (((uint32_t)(uint16_t)dx) << 16);
                const uint32_t pr2 = __shfl_xor((int)pr, 2);
                if ((lane & 3) == 0) {
                    const int d0 = (int)(short)(pr & 0xFFFFu);
                    const int d1 = (int)(short)(pr >> 16);
                    const int d2 = (int)(short)(pr2 & 0xFFFFu);
                    const int d3 = (int)(short)(pr2 >> 16);
                    // carry-compensated field chain (exact)
                    const int c0 = (d0 < 0) ? 1 : 0;
                    const int e1 = d1 - c0;
                    const int c1 = (e1 < 0) ? 1 : 0;
                    const int e2 = d2 - c1;
                    const int c2 = (e2 < 0) ? 1 : 0;
                    const int e3 = d3 - c2;
                    const unsigned long long delta =
                          (unsigned long long)(uint16_t)d0
                        | ((unsigned long long)(uint16_t)e1 << 16)
                        | ((unsigned long long)(uint16_t)e2 << 32)
                        | ((unsigned long long)(uint16_t)e3 << 48);
                    atomicAdd(rbase + n * 4, delta);
                }
            }
        }
    }
}

// ---------------------------------------------------------------------------
// BN stats from packed accumulator.
// ---------------------------------------------------------------------------
__global__ __launch_bounds__(256) void bn_reduce_q(
    const unsigned long long* __restrict__ yq, float* __restrict__ stats)
{
    __shared__ float ls[128];
    if (threadIdx.x < 128) ls[threadIdx.x] = 0.f;
    __syncthreads();

    const int c16 = threadIdx.x & 15;                  // u64 slot in row
    const int row0 = (blockIdx.x * blockDim.x + threadIdx.x) >> 4;
    const int rstride = (gridDim.x * blockDim.x) >> 4;

    float s0=0,s1=0,s2=0,s3=0,q0=0,q1=0,q2=0,q3=0;
    for (int r = row0; r < N_VOX; r += rstride) {
        const unsigned long long v = yq[(size_t)r * 16 + c16];
        const float f0 = (float)((int)( v        & 0xFFFFu) - 0x8000) * QINV;
        const float f1 = (float)((int)((v >> 16) & 0xFFFFu) - 0x8000) * QINV;
        const float f2 = (float)((int)((v >> 32) & 0xFFFFu) - 0x8000) * QINV;
        const float f3 = (float)((int)((v >> 48) & 0xFFFFu) - 0x8000) * QINV;
        s0 += f0; q0 += f0 * f0;
        s1 += f1; q1 += f1 * f1;
        s2 += f2; q2 += f2 * f2;
        s3 += f3; q3 += f3 * f3;
    }
    const int ch = c16 * 4;
    atomicAdd(&ls[ch + 0], s0);  atomicAdd(&ls[64 + ch + 0], q0);
    atomicAdd(&ls[ch + 1], s1);  atomicAdd(&ls[64 + ch + 1], q1);
    atomicAdd(&ls[ch + 2], s2);  atomicAdd(&ls[64 + ch + 2], q2);
    atomicAdd(&ls[ch + 3], s3);  atomicAdd(&ls[64 + ch + 3], q3);
    __syncthreads();
    if (threadIdx.x < 128) atomicAdd(&stats[threadIdx.x], ls[threadIdx.x]);
}

__global__ void bn_finalize(
    const float* __restrict__ stats, const float* __restrict__ gamma,
    const float* __restrict__ beta, float* __restrict__ coef)
{
    const int c = threadIdx.x;
    if (c < 64) {
        const float inv_n = 1.0f / (float)N_VOX;
        const float mean  = stats[c] * inv_n;
        const float var   = stats[64 + c] * inv_n - mean * mean;
        const float scale = gamma[c] * rsqrtf(var + BN_EPS);
        coef[c]      = scale;
        coef[64 + c] = beta[c] - mean * scale;
    }
}

// ---------------------------------------------------------------------------
// Decode + BN + ReLU -> f32 output. One u64 -> one float4 store.
// ---------------------------------------------------------------------------
__global__ __launch_bounds__(256) void bn_apply_q(
    const unsigned long long* __restrict__ yq, const float* __restrict__ coef,
    float4* __restrict__ out4)
{
    const size_t total = (size_t)N_VOX * 16;
    size_t i = (size_t)blockIdx.x * blockDim.x + threadIdx.x;
    const size_t stride = (size_t)gridDim.x * blockDim.x;   // multiple of 16

    const int ch = (int)(i & 15) * 4;
    const float sc0 = coef[ch + 0], sh0 = coef[64 + ch + 0];
    const float sc1 = coef[ch + 1], sh1 = coef[64 + ch + 1];
    const float sc2 = coef[ch + 2], sh2 = coef[64 + ch + 2];
    const float sc3 = coef[ch + 3], sh3 = coef[64 + ch + 3];

    for (; i < total; i += stride) {
        const unsigned long long v = yq[i];
        const float f0 = (float)((int)( v        & 0xFFFFu) - 0x8000) * QINV;
        const float f1 = (float)((int)((v >> 16) & 0xFFFFu) - 0x8000) * QINV;
        const float f2 = (float)((int)((v >> 32) & 0xFFFFu) - 0x8000) * QINV;
        const float f3 = (float)((int)((v >> 48) & 0xFFFFu) - 0x8000) * QINV;
        float4 o;
        o.x = fmaxf(0.f, fmaf(f0, sc0, sh0));
        o.y = fmaxf(0.f, fmaf(f1, sc1, sh1));
        o.z = fmaxf(0.f, fmaf(f2, sc2, sh2));
        o.w = fmaxf(0.f, fmaf(f3, sc3, sh3));
        out4[i] = o;
    }
}

// ==================== fallback tier: f32-atomic path into d_out =============
__global__ __launch_bounds__(256) void conv_mfma(
    const float* __restrict__ x, const float* __restrict__ w,
    const int* __restrict__ kin, const int* __restrict__ kout,
    float* __restrict__ y)
{
    const int lane = threadIdx.x & 63;
    const int wid  = threadIdx.x >> 6;
    const int k    = blockIdx.y;
    const int row  = lane & 15;
    const int kg   = lane >> 4;

    const float* wk = w + (size_t)k * (INC * OUTC);

    bf16x8 bfrag[4][2];
    #pragma unroll
    for (int n = 0; n < 4; ++n) {
        #pragma unroll
        for (int kk = 0; kk < 2; ++kk) {
            const int kbase = kk * 32 + kg * 8;
            const float* bp = wk + (size_t)kbase * OUTC + n * 16 + row;
            bfrag[n][kk] = pack_frag(bp[0*OUTC], bp[1*OUTC], bp[2*OUTC], bp[3*OUTC],
                                     bp[4*OUTC], bp[5*OUTC], bp[6*OUTC], bp[7*OUTC]);
        }
    }

    const int* kin_k  = kin  + (size_t)k * N_PAIRS;
    const int* kout_k = kout + (size_t)k * N_PAIRS;

    const int NCHUNK = N_PAIRS / 16;
    const int nwaves = gridDim.x * 4;

    for (int ch = blockIdx.x * 4 + wid; ch < NCHUNK; ch += nwaves) {
        const int e0 = ch * 16;
        const int in_idx = kin_k[e0 + row];
        const int4 oi = *(const int4*)(kout_k + e0 + kg * 4);

        const float* xr = x + (size_t)in_idx * INC + kg * 8;
        bf16x8 afrag[2];
        #pragma unroll
        for (int kk = 0; kk < 2; ++kk) {
            const f32x4 a0 = *(const f32x4*)(xr + kk * 32);
            const f32x4 a1 = *(const f32x4*)(xr + kk * 32 + 4);
            afrag[kk] = pack_frag(a0.x, a0.y, a0.z, a0.w, a1.x, a1.y, a1.z, a1.w);
        }

        f32x4 acc[4] = {{0,0,0,0},{0,0,0,0},{0,0,0,0},{0,0,0,0}};
        #pragma unroll
        for (int n = 0; n < 4; ++n) {
            acc[n] = __builtin_amdgcn_mfma_f32_16x16x32_bf16(afrag[0], bfrag[n][0], acc[n], 0, 0, 0);
            acc[n] = __builtin_amdgcn_mfma_f32_16x16x32_bf16(afrag[1], bfrag[n][1], acc[n], 0, 0, 0);
        }

        const int orow[4] = {oi.x, oi.y, oi.z, oi.w};
        #pragma unroll
        for (int j = 0; j < 4; ++j) {
            float* base = y + (size_t)orow[j] * OUTC + row;
            unsafeAtomicAdd(base + 0,  acc[0][j]);
            unsafeAtomicAdd(base + 16, acc[1][j]);
            unsafeAtomicAdd(base + 32, acc[2][j]);
            unsafeAtomicAdd(base + 48, acc[3][j]);
        }
    }
}

__global__ __launch_bounds__(256) void bn_reduce(
    const float* __restrict__ y, float* __restrict__ stats)
{
    __shared__ float s_sum[256];
    __shared__ float s_sq[256];

    const int c = threadIdx.x & 63;
    const int row0 = (blockIdx.x * blockDim.x + threadIdx.x) >> 6;
    const int rstride = (gridDim.x * blockDim.x) >> 6;

    float s = 0.f, ss = 0.f;
    for (int r = row0; r < N_VOX; r += rstride) {
        const float v = y[(size_t)r * OUTC + c];
        s += v;
        ss += v * v;
    }
    s_sum[threadIdx.x] = s;
    s_sq[threadIdx.x]  = ss;
    __syncthreads();

    if (threadIdx.x < 64) {
        const float ts  = (s_sum[c] + s_sum[64 + c]) + (s_sum[128 + c] + s_sum[192 + c]);
        const float tss = (s_sq[c]  + s_sq[64 + c])  + (s_sq[128 + c]  + s_sq[192 + c]);
        atomicAdd(&stats[c], ts);
        atomicAdd(&stats[64 + c], tss);
    }
}

__global__ __launch_bounds__(256) void bn_apply(
    float* __restrict__ y, const float* __restrict__ coef)
{
    const size_t total4 = (size_t)N_VOX * OUTC / 4;
    size_t i = (size_t)blockIdx.x * blockDim.x + threadIdx.x;
    const size_t stride = (size_t)gridDim.x * blockDim.x;

    const int c0 = (int)((i * 4) & 63);
    const float sc0 = coef[c0 + 0], sh0 = coef[64 + c0 + 0];
    const float sc1 = coef[c0 + 1], sh1 = coef[64 + c0 + 1];
    const float sc2 = coef[c0 + 2], sh2 = coef[64 + c0 + 2];
    const float sc3 = coef[c0 + 3], sh3 = coef[64 + c0 + 3];

    float4* y4 = (float4*)y;
    for (; i < total4; i += stride) {
        float4 v = y4[i];
        v.x = fmaxf(0.f, fmaf(v.x, sc0, sh0));
        v.y = fmaxf(0.f, fmaf(v.y, sc1, sh1));
        v.z = fmaxf(0.f, fmaf(v.z, sc2, sh2));
        v.w = fmaxf(0.f, fmaf(v.w, sc3, sh3));
        y4[i] = v;
    }
}

extern "C" void kernel_launch(void* const* d_in, const int* in_sizes, int n_in,
                              void* d_out, int out_size, void* d_ws, size_t ws_size,
                              hipStream_t stream)
{
    const float* x     = (const float*)d_in[0];
    const float* w     = (const float*)d_in[1];
    const float* gamma = (const float*)d_in[2];
    const float* beta  = (const float*)d_in[3];
    const int*   kin   = (const int*)d_in[4];
    const int*   kout  = (const int*)d_in[5];

    const size_t yq_bytes = (size_t)N_VOX * 16 * 8;   // 25.6 MB
    const size_t needA = yq_bytes + 1024;

    if (ws_size >= needA) {
        unsigned long long* yq = (unsigned long long*)d_ws;
        float* stats = (float*)((char*)d_ws + yq_bytes);
        float* coef  = stats + 128;

        hipMemsetAsync(stats, 0, 128 * sizeof(float), stream);
        init_q<<<2048, 256, 0, stream>>>(yq);
        conv_q<<<dim3(64, KK), 256, 0, stream>>>(x, w, kin, kout, yq);
        bn_reduce_q<<<512, 256, 0, stream>>>(yq, stats);
        bn_finalize<<<1, 64, 0, stream>>>(stats, gamma, beta, coef);
        bn_apply_q<<<2048, 256, 0, stream>>>(yq, coef, (float4*)d_out);
    } else {
        // f32-atomic fallback (proven): y lives in d_out
        float* y     = (float*)d_out;
        float* stats = (float*)d_ws;
        float* coef  = stats + 128;

        hipMemsetAsync(y, 0, (size_t)N_VOX * OUTC * sizeof(float), stream);
        hipMemsetAsync(stats, 0, 128 * sizeof(float), stream);

        conv_mfma<<<dim3(64, KK), 256, 0, stream>>>(x, w, kin, kout, y);
        bn_reduce<<<512, 256, 0, stream>>>(y, stats);
        bn_finalize<<<1, 64, 0, stream>>>(stats, gamma, beta, coef);
        bn_apply<<<2048, 256, 0, stream>>>(y, coef);
    }
}

// Round 11
// 554.571 us; speedup vs baseline: 2.3446x; 1.0026x over previous
//
#include <hip/hip_runtime.h>
#include <cstdint>

#define N_VOX   200000
#define N_PAIRS 100000
#define KK      27
#define INC     64
#define OUTC    64
#define BN_EPS  1e-5f

// Fixed-point packing: 4 channels x 16-bit biased fixed-point per u64.
// scale 512 (res ~2e-3), bias 0x8000/field. Fields stay within +/-2^14 of
// bias (|y| sums << 32), so no cross-field wrap after carry compensation.
#define QS   512.0f
#define QINV (1.0f / 512.0f)

typedef __attribute__((ext_vector_type(8))) short bf16x8;
typedef __attribute__((ext_vector_type(4))) float f32x4;

__device__ inline uint32_t cvt_pk_bf16(float lo, float hi) {
    uint32_t r;
    asm("v_cvt_pk_bf16_f32 %0, %1, %2" : "=v"(r) : "v"(lo), "v"(hi));
    return r;
}

__device__ inline bf16x8 pack_frag(float a, float b, float c, float d,
                                   float e, float f, float g, float h) {
    union { uint32_t u[4]; bf16x8 v; } cv;
    cv.u[0] = cvt_pk_bf16(a, b);
    cv.u[1] = cvt_pk_bf16(c, d);
    cv.u[2] = cvt_pk_bf16(e, f);
    cv.u[3] = cvt_pk_bf16(g, h);
    return cv.v;
}

__device__ inline bf16x8 as_frag(uint4 u) {
    union { uint4 u; bf16x8 v; } cv; cv.u = u; return cv.v;
}

// ---------------------------------------------------------------------------
// Cast x (f32) -> xb (bf16) rows of 128 B. xb lives in d_out (overwritten by
// bn_apply_q at the end). i handles 8 floats -> one uint4 (8 bf16).
// ---------------------------------------------------------------------------
__global__ __launch_bounds__(256) void xcast(
    const float* __restrict__ x, uint4* __restrict__ xb)
{
    const size_t total = (size_t)N_VOX * 8;
    size_t i = (size_t)blockIdx.x * blockDim.x + threadIdx.x;
    const size_t stride = (size_t)gridDim.x * blockDim.x;
    for (; i < total; i += stride) {
        const float4 a = *(const float4*)(x + i * 8);
        const float4 b = *(const float4*)(x + i * 8 + 4);
        uint4 o;
        o.x = cvt_pk_bf16(a.x, a.y);
        o.y = cvt_pk_bf16(a.z, a.w);
        o.z = cvt_pk_bf16(b.x, b.y);
        o.w = cvt_pk_bf16(b.z, b.w);
        xb[i] = o;
    }
}

// ---------------------------------------------------------------------------
// init: every 16-bit field = 0x8000 (bias) = value 0.
// ---------------------------------------------------------------------------
__global__ __launch_bounds__(256) void init_q(unsigned long long* __restrict__ yq)
{
    const size_t total = (size_t)N_VOX * 16;
    size_t i = (size_t)blockIdx.x * blockDim.x + threadIdx.x;
    const size_t stride = (size_t)gridDim.x * blockDim.x;
    for (; i < total; i += stride) yq[i] = 0x8000800080008000ULL;
}

// ---------------------------------------------------------------------------
// MFMA conv: bf16 pre-cast gather (2 lines/pair) + packed-u64 atomic scatter.
// One wave per 16-pair chunk; blockIdx.y = k. Gathered uint4s ARE A-frags.
// ---------------------------------------------------------------------------
__global__ __launch_bounds__(256) void conv_q(
    const uint4* __restrict__ xb, const float* __restrict__ w,
    const int* __restrict__ kin, const int* __restrict__ kout,
    unsigned long long* __restrict__ yq)
{
    const int lane = threadIdx.x & 63;
    const int wid  = threadIdx.x >> 6;
    const int k    = blockIdx.y;
    const int row  = lane & 15;
    const int kg   = lane >> 4;

    const float* wk = w + (size_t)k * (INC * OUTC);

    bf16x8 bfrag[4][2];
    #pragma unroll
    for (int n = 0; n < 4; ++n) {
        #pragma unroll
        for (int kk = 0; kk < 2; ++kk) {
            const int kbase = kk * 32 + kg * 8;
            const float* bp = wk + (size_t)kbase * OUTC + n * 16 + row;
            bfrag[n][kk] = pack_frag(bp[0*OUTC], bp[1*OUTC], bp[2*OUTC], bp[3*OUTC],
                                     bp[4*OUTC], bp[5*OUTC], bp[6*OUTC], bp[7*OUTC]);
        }
    }

    const int* kin_k  = kin  + (size_t)k * N_PAIRS;
    const int* kout_k = kout + (size_t)k * N_PAIRS;

    const int NCHUNK = N_PAIRS / 16;       // 6250, exact
    const int nwaves = gridDim.x * 4;

    for (int ch = blockIdx.x * 4 + wid; ch < NCHUNK; ch += nwaves) {
        const int e0 = ch * 16;
        const int in_idx = kin_k[e0 + row];
        const int4 oi = *(const int4*)(kout_k + e0 + kg * 4);

        // bf16 row gather: 16B at uint4 slot kg and kg+4 (whole 128B row
        // covered once across the 4 kg groups -> 2 lines per pair).
        const uint4* xr = xb + (size_t)in_idx * 8;
        const bf16x8 a0 = as_frag(xr[kg]);
        const bf16x8 a1 = as_frag(xr[kg + 4]);

        f32x4 acc[4] = {{0,0,0,0},{0,0,0,0},{0,0,0,0},{0,0,0,0}};
        #pragma unroll
        for (int n = 0; n < 4; ++n) {
            acc[n] = __builtin_amdgcn_mfma_f32_16x16x32_bf16(a0, bfrag[n][0], acc[n], 0, 0, 0);
            acc[n] = __builtin_amdgcn_mfma_f32_16x16x32_bf16(a1, bfrag[n][1], acc[n], 0, 0, 0);
        }

        const int orow[4] = {oi.x, oi.y, oi.z, oi.w};
        #pragma unroll
        for (int j = 0; j < 4; ++j) {
            unsigned long long* rbase = yq + (size_t)orow[j] * 16 + (row >> 2);
            #pragma unroll
            for (int n = 0; n < 4; ++n) {
                const float v = fminf(fmaxf(acc[n][j], -31.f), 31.f);
                const int d = __float2int_rn(v * QS);
                const int dx = __shfl_xor(d, 1);
                uint32_t pr = ((uint32_t)(uint16_t)d) | (((uint32_t)(uint16_t)dx) << 16);
                const uint32_t pr2 = __shfl_xor((int)pr, 2);
                if ((lane & 3) == 0) {
                    const int d0 = (int)(short)(pr & 0xFFFFu);
                    const int d1 = (int)(short)(pr >> 16);
                    const int d2 = (int)(short)(pr2 & 0xFFFFu);
                    const int d3 = (int)(short)(pr2 >> 16);
                    const int c0 = (d0 < 0) ? 1 : 0;
                    const int e1 = d1 - c0;
                    const int c1 = (e1 < 0) ? 1 : 0;
                    const int e2 = d2 - c1;
                    const int c2 = (e2 < 0) ? 1 : 0;
                    const int e3 = d3 - c2;
                    const unsigned long long delta =
                          (unsigned long long)(uint16_t)d0
                        | ((unsigned long long)(uint16_t)e1 << 16)
                        | ((unsigned long long)(uint16_t)e2 << 32)
                        | ((unsigned long long)(uint16_t)e3 << 48);
                    atomicAdd(rbase + n * 4, delta);
                }
            }
        }
    }
}

// ---------------------------------------------------------------------------
// BN stats from packed accumulator.
// ---------------------------------------------------------------------------
__global__ __launch_bounds__(256) void bn_reduce_q(
    const unsigned long long* __restrict__ yq, float* __restrict__ stats)
{
    __shared__ float ls[128];
    if (threadIdx.x < 128) ls[threadIdx.x] = 0.f;
    __syncthreads();

    const int c16 = threadIdx.x & 15;
    const int row0 = (blockIdx.x * blockDim.x + threadIdx.x) >> 4;
    const int rstride = (gridDim.x * blockDim.x) >> 4;

    float s0=0,s1=0,s2=0,s3=0,q0=0,q1=0,q2=0,q3=0;
    for (int r = row0; r < N_VOX; r += rstride) {
        const unsigned long long v = yq[(size_t)r * 16 + c16];
        const float f0 = (float)((int)( v        & 0xFFFFu) - 0x8000) * QINV;
        const float f1 = (float)((int)((v >> 16) & 0xFFFFu) - 0x8000) * QINV;
        const float f2 = (float)((int)((v >> 32) & 0xFFFFu) - 0x8000) * QINV;
        const float f3 = (float)((int)((v >> 48) & 0xFFFFu) - 0x8000) * QINV;
        s0 += f0; q0 += f0 * f0;
        s1 += f1; q1 += f1 * f1;
        s2 += f2; q2 += f2 * f2;
        s3 += f3; q3 += f3 * f3;
    }
    const int ch = c16 * 4;
    atomicAdd(&ls[ch + 0], s0);  atomicAdd(&ls[64 + ch + 0], q0);
    atomicAdd(&ls[ch + 1], s1);  atomicAdd(&ls[64 + ch + 1], q1);
    atomicAdd(&ls[ch + 2], s2);  atomicAdd(&ls[64 + ch + 2], q2);
    atomicAdd(&ls[ch + 3], s3);  atomicAdd(&ls[64 + ch + 3], q3);
    __syncthreads();
    if (threadIdx.x < 128) atomicAdd(&stats[threadIdx.x], ls[threadIdx.x]);
}

__global__ void bn_finalize(
    const float* __restrict__ stats, const float* __restrict__ gamma,
    const float* __restrict__ beta, float* __restrict__ coef)
{
    const int c = threadIdx.x;
    if (c < 64) {
        const float inv_n = 1.0f / (float)N_VOX;
        const float mean  = stats[c] * inv_n;
        const float var   = stats[64 + c] * inv_n - mean * mean;
        const float scale = gamma[c] * rsqrtf(var + BN_EPS);
        coef[c]      = scale;
        coef[64 + c] = beta[c] - mean * scale;
    }
}

// ---------------------------------------------------------------------------
// Decode + BN + ReLU -> f32 output (overwrites all of d_out, incl. xb).
// ---------------------------------------------------------------------------
__global__ __launch_bounds__(256) void bn_apply_q(
    const unsigned long long* __restrict__ yq, const float* __restrict__ coef,
    float4* __restrict__ out4)
{
    const size_t total = (size_t)N_VOX * 16;
    size_t i = (size_t)blockIdx.x * blockDim.x + threadIdx.x;
    const size_t stride = (size_t)gridDim.x * blockDim.x;   // multiple of 16

    const int ch = (int)(i & 15) * 4;
    const float sc0 = coef[ch + 0], sh0 = coef[64 + ch + 0];
    const float sc1 = coef[ch + 1], sh1 = coef[64 + ch + 1];
    const float sc2 = coef[ch + 2], sh2 = coef[64 + ch + 2];
    const float sc3 = coef[ch + 3], sh3 = coef[64 + ch + 3];

    for (; i < total; i += stride) {
        const unsigned long long v = yq[i];
        const float f0 = (float)((int)( v        & 0xFFFFu) - 0x8000) * QINV;
        const float f1 = (float)((int)((v >> 16) & 0xFFFFu) - 0x8000) * QINV;
        const float f2 = (float)((int)((v >> 32) & 0xFFFFu) - 0x8000) * QINV;
        const float f3 = (float)((int)((v >> 48) & 0xFFFFu) - 0x8000) * QINV;
        float4 o;
        o.x = fmaxf(0.f, fmaf(f0, sc0, sh0));
        o.y = fmaxf(0.f, fmaf(f1, sc1, sh1));
        o.z = fmaxf(0.f, fmaf(f2, sc2, sh2));
        o.w = fmaxf(0.f, fmaf(f3, sc3, sh3));
        out4[i] = o;
    }
}

// ==================== fallback tier: f32-atomic path into d_out =============
__global__ __launch_bounds__(256) void conv_mfma(
    const float* __restrict__ x, const float* __restrict__ w,
    const int* __restrict__ kin, const int* __restrict__ kout,
    float* __restrict__ y)
{
    const int lane = threadIdx.x & 63;
    const int wid  = threadIdx.x >> 6;
    const int k    = blockIdx.y;
    const int row  = lane & 15;
    const int kg   = lane >> 4;

    const float* wk = w + (size_t)k * (INC * OUTC);

    bf16x8 bfrag[4][2];
    #pragma unroll
    for (int n = 0; n < 4; ++n) {
        #pragma unroll
        for (int kk = 0; kk < 2; ++kk) {
            const int kbase = kk * 32 + kg * 8;
            const float* bp = wk + (size_t)kbase * OUTC + n * 16 + row;
            bfrag[n][kk] = pack_frag(bp[0*OUTC], bp[1*OUTC], bp[2*OUTC], bp[3*OUTC],
                                     bp[4*OUTC], bp[5*OUTC], bp[6*OUTC], bp[7*OUTC]);
        }
    }

    const int* kin_k  = kin  + (size_t)k * N_PAIRS;
    const int* kout_k = kout + (size_t)k * N_PAIRS;

    const int NCHUNK = N_PAIRS / 16;
    const int nwaves = gridDim.x * 4;

    for (int ch = blockIdx.x * 4 + wid; ch < NCHUNK; ch += nwaves) {
        const int e0 = ch * 16;
        const int in_idx = kin_k[e0 + row];
        const int4 oi = *(const int4*)(kout_k + e0 + kg * 4);

        const float* xr = x + (size_t)in_idx * INC + kg * 8;
        bf16x8 afrag[2];
        #pragma unroll
        for (int kk = 0; kk < 2; ++kk) {
            const f32x4 a0 = *(const f32x4*)(xr + kk * 32);
            const f32x4 a1 = *(const f32x4*)(xr + kk * 32 + 4);
            afrag[kk] = pack_frag(a0.x, a0.y, a0.z, a0.w, a1.x, a1.y, a1.z, a1.w);
        }

        f32x4 acc[4] = {{0,0,0,0},{0,0,0,0},{0,0,0,0},{0,0,0,0}};
        #pragma unroll
        for (int n = 0; n < 4; ++n) {
            acc[n] = __builtin_amdgcn_mfma_f32_16x16x32_bf16(afrag[0], bfrag[n][0], acc[n], 0, 0, 0);
            acc[n] = __builtin_amdgcn_mfma_f32_16x16x32_bf16(afrag[1], bfrag[n][1], acc[n], 0, 0, 0);
        }

        const int orow[4] = {oi.x, oi.y, oi.z, oi.w};
        #pragma unroll
        for (int j = 0; j < 4; ++j) {
            float* base = y + (size_t)orow[j] * OUTC + row;
            unsafeAtomicAdd(base + 0,  acc[0][j]);
            unsafeAtomicAdd(base + 16, acc[1][j]);
            unsafeAtomicAdd(base + 32, acc[2][j]);
            unsafeAtomicAdd(base + 48, acc[3][j]);
        }
    }
}

__global__ __launch_bounds__(256) void bn_reduce(
    const float* __restrict__ y, float* __restrict__ stats)
{
    __shared__ float s_sum[256];
    __shared__ float s_sq[256];

    const int c = threadIdx.x & 63;
    const int row0 = (blockIdx.x * blockDim.x + threadIdx.x) >> 6;
    const int rstride = (gridDim.x * blockDim.x) >> 6;

    float s = 0.f, ss = 0.f;
    for (int r = row0; r < N_VOX; r += rstride) {
        const float v = y[(size_t)r * OUTC + c];
        s += v;
        ss += v * v;
    }
    s_sum[threadIdx.x] = s;
    s_sq[threadIdx.x]  = ss;
    __syncthreads();

    if (threadIdx.x < 64) {
        const float ts  = (s_sum[c] + s_sum[64 + c]) + (s_sum[128 + c] + s_sum[192 + c]);
        const float tss = (s_sq[c]  + s_sq[64 + c])  + (s_sq[128 + c]  + s_sq[192 + c]);
        atomicAdd(&stats[c], ts);
        atomicAdd(&stats[64 + c], tss);
    }
}

__global__ __launch_bounds__(256) void bn_apply(
    float* __restrict__ y, const float* __restrict__ coef)
{
    const size_t total4 = (size_t)N_VOX * OUTC / 4;
    size_t i = (size_t)blockIdx.x * blockDim.x + threadIdx.x;
    const size_t stride = (size_t)gridDim.x * blockDim.x;

    const int c0 = (int)((i * 4) & 63);
    const float sc0 = coef[c0 + 0], sh0 = coef[64 + c0 + 0];
    const float sc1 = coef[c0 + 1], sh1 = coef[64 + c0 + 1];
    const float sc2 = coef[c0 + 2], sh2 = coef[64 + c0 + 2];
    const float sc3 = coef[c0 + 3], sh3 = coef[64 + c0 + 3];

    float4* y4 = (float4*)y;
    for (; i < total4; i += stride) {
        float4 v = y4[i];
        v.x = fmaxf(0.f, fmaf(v.x, sc0, sh0));
        v.y = fmaxf(0.f, fmaf(v.y, sc1, sh1));
        v.z = fmaxf(0.f, fmaf(v.z, sc2, sh2));
        v.w = fmaxf(0.f, fmaf(v.w, sc3, sh3));
        y4[i] = v;
    }
}

extern "C" void kernel_launch(void* const* d_in, const int* in_sizes, int n_in,
                              void* d_out, int out_size, void* d_ws, size_t ws_size,
                              hipStream_t stream)
{
    const float* x     = (const float*)d_in[0];
    const float* w     = (const float*)d_in[1];
    const float* gamma = (const float*)d_in[2];
    const float* beta  = (const float*)d_in[3];
    const int*   kin   = (const int*)d_in[4];
    const int*   kout  = (const int*)d_in[5];

    const size_t yq_bytes = (size_t)N_VOX * 16 * 8;   // 25.6 MB
    const size_t needA = yq_bytes + 1024;

    if (ws_size >= needA) {
        unsigned long long* yq = (unsigned long long*)d_ws;
        float* stats = (float*)((char*)d_ws + yq_bytes);
        float* coef  = stats + 128;
        uint4* xb    = (uint4*)d_out;                 // bf16 x inside d_out

        hipMemsetAsync(stats, 0, 128 * sizeof(float), stream);
        xcast<<<2048, 256, 0, stream>>>(x, xb);
        init_q<<<2048, 256, 0, stream>>>(yq);
        conv_q<<<dim3(64, KK), 256, 0, stream>>>(xb, w, kin, kout, yq);
        bn_reduce_q<<<512, 256, 0, stream>>>(yq, stats);
        bn_finalize<<<1, 64, 0, stream>>>(stats, gamma, beta, coef);
        bn_apply_q<<<2048, 256, 0, stream>>>(yq, coef, (float4*)d_out);
    } else {
        // f32-atomic fallback (proven): y lives in d_out
        float* y     = (float*)d_out;
        float* stats = (float*)d_ws;
        float* coef  = stats + 128;

        hipMemsetAsync(y, 0, (size_t)N_VOX * OUTC * sizeof(float), stream);
        hipMemsetAsync(stats, 0, 128 * sizeof(float), stream);

        conv_mfma<<<dim3(64, KK), 256, 0, stream>>>(x, w, kin, kout, y);
        bn_reduce<<<512, 256, 0, stream>>>(y, stats);
        bn_finalize<<<1, 64, 0, stream>>>(stats, gamma, beta, coef);
        bn_apply<<<2048, 256, 0, stream>>>(y, coef);
    }
}

// Round 12
// 315.702 us; speedup vs baseline: 4.1186x; 1.7566x over previous
//
#include <hip/hip_runtime.h>
#include <cstdint>

#define N_VOX   200000
#define N_PAIRS 100000
#define KK      27
#define INC     64
#define OUTC    64
#define BN_EPS  1e-5f

// Fixed-point: 4 channels x signed 16-bit per u64, scale 512 (res ~2e-3).
// Carry-compensated encoding is exact under u64 adds; fields never exceed
// +/-2^15 (per-channel sums have std ~0.6 -> |field| ~< 2000). Zero-init.
#define QS   512.0f
#define QINV (1.0f / 512.0f)

typedef __attribute__((ext_vector_type(8))) short bf16x8;
typedef __attribute__((ext_vector_type(4))) float f32x4;

__device__ inline uint32_t cvt_pk_bf16(float lo, float hi) {
    uint32_t r;
    asm("v_cvt_pk_bf16_f32 %0, %1, %2" : "=v"(r) : "v"(lo), "v"(hi));
    return r;
}

__device__ inline bf16x8 pack_frag(float a, float b, float c, float d,
                                   float e, float f, float g, float h) {
    union { uint32_t u[4]; bf16x8 v; } cv;
    cv.u[0] = cvt_pk_bf16(a, b);
    cv.u[1] = cvt_pk_bf16(c, d);
    cv.u[2] = cvt_pk_bf16(e, f);
    cv.u[3] = cvt_pk_bf16(g, h);
    return cv.v;
}

__device__ inline bf16x8 as_frag(uint4 u) {
    union { uint4 u; bf16x8 v; } cv; cv.u = u; return cv.v;
}

// ---------------------------------------------------------------------------
// Cast x (f32) -> xb (bf16) rows of 128 B. xb lives in d_out (overwritten by
// bn_apply_q at the end).
// ---------------------------------------------------------------------------
__global__ __launch_bounds__(256) void xcast(
    const float* __restrict__ x, uint4* __restrict__ xb)
{
    const size_t total = (size_t)N_VOX * 8;
    size_t i = (size_t)blockIdx.x * blockDim.x + threadIdx.x;
    const size_t stride = (size_t)gridDim.x * blockDim.x;
    for (; i < total; i += stride) {
        const float4 a = *(const float4*)(x + i * 8);
        const float4 b = *(const float4*)(x + i * 8 + 4);
        uint4 o;
        o.x = cvt_pk_bf16(a.x, a.y);
        o.y = cvt_pk_bf16(a.z, a.w);
        o.z = cvt_pk_bf16(b.x, b.y);
        o.w = cvt_pk_bf16(b.z, b.w);
        xb[i] = o;
    }
}

// ---------------------------------------------------------------------------
// MFMA conv: bf16 gather (2 lines/pair) + full-line packed-u64 atomic scatter.
// Scatter restructured: per pair-group j, TWO atomic instructions with 32
// active lanes each; per kg-group the 8 lanes cover 8 consecutive u64 = one
// whole 64B line -> 4 transactions/instruction, 32 transactions/chunk (was 64).
// ---------------------------------------------------------------------------
__global__ __launch_bounds__(256) void conv_q(
    const uint4* __restrict__ xb, const float* __restrict__ w,
    const int* __restrict__ kin, const int* __restrict__ kout,
    unsigned long long* __restrict__ yq)
{
    const int lane = threadIdx.x & 63;
    const int wid  = threadIdx.x >> 6;
    const int k    = blockIdx.y;
    const int row  = lane & 15;
    const int kg   = lane >> 4;

    const float* wk = w + (size_t)k * (INC * OUTC);

    bf16x8 bfrag[4][2];
    #pragma unroll
    for (int n = 0; n < 4; ++n) {
        #pragma unroll
        for (int kk = 0; kk < 2; ++kk) {
            const int kbase = kk * 32 + kg * 8;
            const float* bp = wk + (size_t)kbase * OUTC + n * 16 + row;
            bfrag[n][kk] = pack_frag(bp[0*OUTC], bp[1*OUTC], bp[2*OUTC], bp[3*OUTC],
                                     bp[4*OUTC], bp[5*OUTC], bp[6*OUTC], bp[7*OUTC]);
        }
    }

    const int* kin_k  = kin  + (size_t)k * N_PAIRS;
    const int* kout_k = kout + (size_t)k * N_PAIRS;

    const int NCHUNK = N_PAIRS / 16;       // 6250, exact
    const int nwaves = gridDim.x * 4;

    for (int ch = blockIdx.x * 4 + wid; ch < NCHUNK; ch += nwaves) {
        const int e0 = ch * 16;
        const int in_idx = kin_k[e0 + row];
        const int4 oi = *(const int4*)(kout_k + e0 + kg * 4);

        const uint4* xr = xb + (size_t)in_idx * 8;
        const bf16x8 a0 = as_frag(xr[kg]);
        const bf16x8 a1 = as_frag(xr[kg + 4]);

        f32x4 acc[4] = {{0,0,0,0},{0,0,0,0},{0,0,0,0},{0,0,0,0}};
        #pragma unroll
        for (int n = 0; n < 4; ++n) {
            acc[n] = __builtin_amdgcn_mfma_f32_16x16x32_bf16(a0, bfrag[n][0], acc[n], 0, 0, 0);
            acc[n] = __builtin_amdgcn_mfma_f32_16x16x32_bf16(a1, bfrag[n][1], acc[n], 0, 0, 0);
        }

        const int orow[4] = {oi.x, oi.y, oi.z, oi.w};
        #pragma unroll
        for (int j = 0; j < 4; ++j) {
            // Build 4 u64 deltas (one per n) at lanes with row%4==0.
            unsigned long long del[4];
            #pragma unroll
            for (int n = 0; n < 4; ++n) {
                const float v = fminf(fmaxf(acc[n][j], -31.f), 31.f);
                const int d = __float2int_rn(v * QS);
                const int dx = __shfl_xor(d, 1);
                uint32_t pr = ((uint32_t)(uint16_t)d) | (((uint32_t)(uint16_t)dx) << 16);
                const uint32_t pr2 = __shfl_xor((int)pr, 2);
                const int d0 = (int)(short)(pr & 0xFFFFu);
                const int d1 = (int)(short)(pr >> 16);
                const int d2 = (int)(short)(pr2 & 0xFFFFu);
                const int d3 = (int)(short)(pr2 >> 16);
                const int c0 = (d0 < 0) ? 1 : 0;
                const int e1 = d1 - c0;
                const int c1 = (e1 < 0) ? 1 : 0;
                const int e2 = d2 - c1;
                const int c2 = (e2 < 0) ? 1 : 0;
                const int e3 = d3 - c2;
                del[n] = (unsigned long long)(uint16_t)d0
                       | ((unsigned long long)(uint16_t)e1 << 16)
                       | ((unsigned long long)(uint16_t)e2 << 32)
                       | ((unsigned long long)(uint16_t)e3 << 48);
            }
            // Move odd-n deltas to the row&2 lanes so 8 lanes/kg cover a line.
            const unsigned long long m1 = __shfl_xor(del[1], 2);
            const unsigned long long m3 = __shfl_xor(del[3], 2);
            if ((lane & 1) == 0) {
                const int u  = row >> 2;
                const bool hi = (row & 2) != 0;
                unsigned long long* rbase = yq + (size_t)orow[j] * 16;
                const unsigned long long dA = hi ? m1 : del[0];
                const int sA = hi ? (4 + u) : u;            // slots 0..7  (line 0)
                atomicAdd(rbase + sA, dA);
                const unsigned long long dB = hi ? m3 : del[2];
                const int sB = hi ? (12 + u) : (8 + u);     // slots 8..15 (line 1)
                atomicAdd(rbase + sB, dB);
            }
        }
    }
}

// ---------------------------------------------------------------------------
// BN stats from packed accumulator (signed fields, zero bias).
// ---------------------------------------------------------------------------
__global__ __launch_bounds__(256) void bn_reduce_q(
    const unsigned long long* __restrict__ yq, float* __restrict__ stats)
{
    __shared__ float ls[128];
    if (threadIdx.x < 128) ls[threadIdx.x] = 0.f;
    __syncthreads();

    const int c16 = threadIdx.x & 15;
    const int row0 = (blockIdx.x * blockDim.x + threadIdx.x) >> 4;
    const int rstride = (gridDim.x * blockDim.x) >> 4;

    float s0=0,s1=0,s2=0,s3=0,q0=0,q1=0,q2=0,q3=0;
    for (int r = row0; r < N_VOX; r += rstride) {
        const unsigned long long v = yq[(size_t)r * 16 + c16];
        const float f0 = (float)((int)(short)( v        & 0xFFFFu)) * QINV;
        const float f1 = (float)((int)(short)((v >> 16) & 0xFFFFu)) * QINV;
        const float f2 = (float)((int)(short)((v >> 32) & 0xFFFFu)) * QINV;
        const float f3 = (float)((int)(short)((v >> 48) & 0xFFFFu)) * QINV;
        s0 += f0; q0 += f0 * f0;
        s1 += f1; q1 += f1 * f1;
        s2 += f2; q2 += f2 * f2;
        s3 += f3; q3 += f3 * f3;
    }
    const int ch = c16 * 4;
    atomicAdd(&ls[ch + 0], s0);  atomicAdd(&ls[64 + ch + 0], q0);
    atomicAdd(&ls[ch + 1], s1);  atomicAdd(&ls[64 + ch + 1], q1);
    atomicAdd(&ls[ch + 2], s2);  atomicAdd(&ls[64 + ch + 2], q2);
    atomicAdd(&ls[ch + 3], s3);  atomicAdd(&ls[64 + ch + 3], q3);
    __syncthreads();
    if (threadIdx.x < 128) atomicAdd(&stats[threadIdx.x], ls[threadIdx.x]);
}

__global__ void bn_finalize(
    const float* __restrict__ stats, const float* __restrict__ gamma,
    const float* __restrict__ beta, float* __restrict__ coef)
{
    const int c = threadIdx.x;
    if (c < 64) {
        const float inv_n = 1.0f / (float)N_VOX;
        const float mean  = stats[c] * inv_n;
        const float var   = stats[64 + c] * inv_n - mean * mean;
        const float scale = gamma[c] * rsqrtf(var + BN_EPS);
        coef[c]      = scale;
        coef[64 + c] = beta[c] - mean * scale;
    }
}

// ---------------------------------------------------------------------------
// Decode + BN + ReLU -> f32 output (overwrites all of d_out, incl. xb).
// ---------------------------------------------------------------------------
__global__ __launch_bounds__(256) void bn_apply_q(
    const unsigned long long* __restrict__ yq, const float* __restrict__ coef,
    float4* __restrict__ out4)
{
    const size_t total = (size_t)N_VOX * 16;
    size_t i = (size_t)blockIdx.x * blockDim.x + threadIdx.x;
    const size_t stride = (size_t)gridDim.x * blockDim.x;   // multiple of 16

    const int ch = (int)(i & 15) * 4;
    const float sc0 = coef[ch + 0], sh0 = coef[64 + ch + 0];
    const float sc1 = coef[ch + 1], sh1 = coef[64 + ch + 1];
    const float sc2 = coef[ch + 2], sh2 = coef[64 + ch + 2];
    const float sc3 = coef[ch + 3], sh3 = coef[64 + ch + 3];

    for (; i < total; i += stride) {
        const unsigned long long v = yq[i];
        const float f0 = (float)((int)(short)( v        & 0xFFFFu)) * QINV;
        const float f1 = (float)((int)(short)((v >> 16) & 0xFFFFu)) * QINV;
        const float f2 = (float)((int)(short)((v >> 32) & 0xFFFFu)) * QINV;
        const float f3 = (float)((int)(short)((v >> 48) & 0xFFFFu)) * QINV;
        float4 o;
        o.x = fmaxf(0.f, fmaf(f0, sc0, sh0));
        o.y = fmaxf(0.f, fmaf(f1, sc1, sh1));
        o.z = fmaxf(0.f, fmaf(f2, sc2, sh2));
        o.w = fmaxf(0.f, fmaf(f3, sc3, sh3));
        out4[i] = o;
    }
}

// ==================== fallback tier: f32-atomic path into d_out =============
__global__ __launch_bounds__(256) void conv_mfma(
    const float* __restrict__ x, const float* __restrict__ w,
    const int* __restrict__ kin, const int* __restrict__ kout,
    float* __restrict__ y)
{
    const int lane = threadIdx.x & 63;
    const int wid  = threadIdx.x >> 6;
    const int k    = blockIdx.y;
    const int row  = lane & 15;
    const int kg   = lane >> 4;

    const float* wk = w + (size_t)k * (INC * OUTC);

    bf16x8 bfrag[4][2];
    #pragma unroll
    for (int n = 0; n < 4; ++n) {
        #pragma unroll
        for (int kk = 0; kk < 2; ++kk) {
            const int kbase = kk * 32 + kg * 8;
            const float* bp = wk + (size_t)kbase * OUTC + n * 16 + row;
            bfrag[n][kk] = pack_frag(bp[0*OUTC], bp[1*OUTC], bp[2*OUTC], bp[3*OUTC],
                                     bp[4*OUTC], bp[5*OUTC], bp[6*OUTC], bp[7*OUTC]);
        }
    }

    const int* kin_k  = kin  + (size_t)k * N_PAIRS;
    const int* kout_k = kout + (size_t)k * N_PAIRS;

    const int NCHUNK = N_PAIRS / 16;
    const int nwaves = gridDim.x * 4;

    for (int ch = blockIdx.x * 4 + wid; ch < NCHUNK; ch += nwaves) {
        const int e0 = ch * 16;
        const int in_idx = kin_k[e0 + row];
        const int4 oi = *(const int4*)(kout_k + e0 + kg * 4);

        const float* xr = x + (size_t)in_idx * INC + kg * 8;
        bf16x8 afrag[2];
        #pragma unroll
        for (int kk = 0; kk < 2; ++kk) {
            const f32x4 a0 = *(const f32x4*)(xr + kk * 32);
            const f32x4 a1 = *(const f32x4*)(xr + kk * 32 + 4);
            afrag[kk] = pack_frag(a0.x, a0.y, a0.z, a0.w, a1.x, a1.y, a1.z, a1.w);
        }

        f32x4 acc[4] = {{0,0,0,0},{0,0,0,0},{0,0,0,0},{0,0,0,0}};
        #pragma unroll
        for (int n = 0; n < 4; ++n) {
            acc[n] = __builtin_amdgcn_mfma_f32_16x16x32_bf16(afrag[0], bfrag[n][0], acc[n], 0, 0, 0);
            acc[n] = __builtin_amdgcn_mfma_f32_16x16x32_bf16(afrag[1], bfrag[n][1], acc[n], 0, 0, 0);
        }

        const int orow[4] = {oi.x, oi.y, oi.z, oi.w};
        #pragma unroll
        for (int j = 0; j < 4; ++j) {
            float* base = y + (size_t)orow[j] * OUTC + row;
            unsafeAtomicAdd(base + 0,  acc[0][j]);
            unsafeAtomicAdd(base + 16, acc[1][j]);
            unsafeAtomicAdd(base + 32, acc[2][j]);
            unsafeAtomicAdd(base + 48, acc[3][j]);
        }
    }
}

__global__ __launch_bounds__(256) void bn_reduce(
    const float* __restrict__ y, float* __restrict__ stats)
{
    __shared__ float s_sum[256];
    __shared__ float s_sq[256];

    const int c = threadIdx.x & 63;
    const int row0 = (blockIdx.x * blockDim.x + threadIdx.x) >> 6;
    const int rstride = (gridDim.x * blockDim.x) >> 6;

    float s = 0.f, ss = 0.f;
    for (int r = row0; r < N_VOX; r += rstride) {
        const float v = y[(size_t)r * OUTC + c];
        s += v;
        ss += v * v;
    }
    s_sum[threadIdx.x] = s;
    s_sq[threadIdx.x]  = ss;
    __syncthreads();

    if (threadIdx.x < 64) {
        const float ts  = (s_sum[c] + s_sum[64 + c]) + (s_sum[128 + c] + s_sum[192 + c]);
        const float tss = (s_sq[c]  + s_sq[64 + c])  + (s_sq[128 + c]  + s_sq[192 + c]);
        atomicAdd(&stats[c], ts);
        atomicAdd(&stats[64 + c], tss);
    }
}

__global__ __launch_bounds__(256) void bn_apply(
    float* __restrict__ y, const float* __restrict__ coef)
{
    const size_t total4 = (size_t)N_VOX * OUTC / 4;
    size_t i = (size_t)blockIdx.x * blockDim.x + threadIdx.x;
    const size_t stride = (size_t)gridDim.x * blockDim.x;

    const int c0 = (int)((i * 4) & 63);
    const float sc0 = coef[c0 + 0], sh0 = coef[64 + c0 + 0];
    const float sc1 = coef[c0 + 1], sh1 = coef[64 + c0 + 1];
    const float sc2 = coef[c0 + 2], sh2 = coef[64 + c0 + 2];
    const float sc3 = coef[c0 + 3], sh3 = coef[64 + c0 + 3];

    float4* y4 = (float4*)y;
    for (; i < total4; i += stride) {
        float4 v = y4[i];
        v.x = fmaxf(0.f, fmaf(v.x, sc0, sh0));
        v.y = fmaxf(0.f, fmaf(v.y, sc1, sh1));
        v.z = fmaxf(0.f, fmaf(v.z, sc2, sh2));
        v.w = fmaxf(0.f, fmaf(v.w, sc3, sh3));
        y4[i] = v;
    }
}

extern "C" void kernel_launch(void* const* d_in, const int* in_sizes, int n_in,
                              void* d_out, int out_size, void* d_ws, size_t ws_size,
                              hipStream_t stream)
{
    const float* x     = (const float*)d_in[0];
    const float* w     = (const float*)d_in[1];
    const float* gamma = (const float*)d_in[2];
    const float* beta  = (const float*)d_in[3];
    const int*   kin   = (const int*)d_in[4];
    const int*   kout  = (const int*)d_in[5];

    const size_t yq_bytes = (size_t)N_VOX * 16 * 8;   // 25.6 MB
    const size_t needA = yq_bytes + 1024;

    if (ws_size >= needA) {
        unsigned long long* yq = (unsigned long long*)d_ws;
        float* stats = (float*)((char*)d_ws + yq_bytes);
        float* coef  = stats + 128;
        uint4* xb    = (uint4*)d_out;                 // bf16 x inside d_out

        hipMemsetAsync(yq, 0, yq_bytes, stream);      // zero-bias accumulator
        hipMemsetAsync(stats, 0, 128 * sizeof(float), stream);
        xcast<<<2048, 256, 0, stream>>>(x, xb);
        conv_q<<<dim3(128, KK), 256, 0, stream>>>(xb, w, kin, kout, yq);
        bn_reduce_q<<<512, 256, 0, stream>>>(yq, stats);
        bn_finalize<<<1, 64, 0, stream>>>(stats, gamma, beta, coef);
        bn_apply_q<<<2048, 256, 0, stream>>>(yq, coef, (float4*)d_out);
    } else {
        // f32-atomic fallback (proven): y lives in d_out
        float* y     = (float*)d_out;
        float* stats = (float*)d_ws;
        float* coef  = stats + 128;

        hipMemsetAsync(y, 0, (size_t)N_VOX * OUTC * sizeof(float), stream);
        hipMemsetAsync(stats, 0, 128 * sizeof(float), stream);

        conv_mfma<<<dim3(64, KK), 256, 0, stream>>>(x, w, kin, kout, y);
        bn_reduce<<<512, 256, 0, stream>>>(y, stats);
        bn_finalize<<<1, 64, 0, stream>>>(stats, gamma, beta, coef);
        bn_apply<<<2048, 256, 0, stream>>>(y, coef);
    }
}

// Round 13
// 315.065 us; speedup vs baseline: 4.1269x; 1.0020x over previous
//
#include <hip/hip_runtime.h>
#include <cstdint>

#define N_VOX   200000
#define N_PAIRS 100000
#define KK      27
#define INC     64
#define OUTC    64
#define BN_EPS  1e-5f

// Fixed-point: 4 channels x signed 16-bit per u64, scale 512 (res ~2e-3).
// Carry-compensated encoding is exact under u64 adds; fields stay well
// within +/-2^15. Zero-init accumulator.
#define QS   512.0f
#define QINV (1.0f / 512.0f)

typedef __attribute__((ext_vector_type(8))) short bf16x8;
typedef __attribute__((ext_vector_type(4))) float f32x4;

__device__ inline uint32_t cvt_pk_bf16(float lo, float hi) {
    uint32_t r;
    asm("v_cvt_pk_bf16_f32 %0, %1, %2" : "=v"(r) : "v"(lo), "v"(hi));
    return r;
}

__device__ inline bf16x8 pack_frag(float a, float b, float c, float d,
                                   float e, float f, float g, float h) {
    union { uint32_t u[4]; bf16x8 v; } cv;
    cv.u[0] = cvt_pk_bf16(a, b);
    cv.u[1] = cvt_pk_bf16(c, d);
    cv.u[2] = cvt_pk_bf16(e, f);
    cv.u[3] = cvt_pk_bf16(g, h);
    return cv.v;
}

__device__ inline bf16x8 as_frag(uint4 u) {
    union { uint4 u; bf16x8 v; } cv; cv.u = u; return cv.v;
}

__device__ inline float dec_lo(uint32_t u) { return (float)((int)(short)(u & 0xFFFFu)) * QINV; }
__device__ inline float dec_hi(uint32_t u) { return (float)((int)(short)(u >> 16))     * QINV; }

// ---------------------------------------------------------------------------
// Cast x (f32) -> xb (bf16) rows of 128 B. xb lives in d_out (overwritten by
// bn_apply_q at the end).
// ---------------------------------------------------------------------------
__global__ __launch_bounds__(256) void xcast(
    const float* __restrict__ x, uint4* __restrict__ xb)
{
    const size_t total = (size_t)N_VOX * 8;
    size_t i = (size_t)blockIdx.x * blockDim.x + threadIdx.x;
    const size_t stride = (size_t)gridDim.x * blockDim.x;
    for (; i < total; i += stride) {
        const float4 a = *(const float4*)(x + i * 8);
        const float4 b = *(const float4*)(x + i * 8 + 4);
        uint4 o;
        o.x = cvt_pk_bf16(a.x, a.y);
        o.y = cvt_pk_bf16(a.z, a.w);
        o.z = cvt_pk_bf16(b.x, b.y);
        o.w = cvt_pk_bf16(b.z, b.w);
        xb[i] = o;
    }
}

// ---------------------------------------------------------------------------
// MFMA conv: bf16 gather (2 lines/pair) + full-line packed-u64 atomic scatter
// (2 lines/pair). Per pair-group j: TWO atomic instructions, 32 active lanes,
// each kg-group's 8 lanes covering one whole 64B line.
// ---------------------------------------------------------------------------
__global__ __launch_bounds__(256) void conv_q(
    const uint4* __restrict__ xb, const float* __restrict__ w,
    const int* __restrict__ kin, const int* __restrict__ kout,
    unsigned long long* __restrict__ yq)
{
    const int lane = threadIdx.x & 63;
    const int wid  = threadIdx.x >> 6;
    const int k    = blockIdx.y;
    const int row  = lane & 15;
    const int kg   = lane >> 4;

    const float* wk = w + (size_t)k * (INC * OUTC);

    bf16x8 bfrag[4][2];
    #pragma unroll
    for (int n = 0; n < 4; ++n) {
        #pragma unroll
        for (int kk = 0; kk < 2; ++kk) {
            const int kbase = kk * 32 + kg * 8;
            const float* bp = wk + (size_t)kbase * OUTC + n * 16 + row;
            bfrag[n][kk] = pack_frag(bp[0*OUTC], bp[1*OUTC], bp[2*OUTC], bp[3*OUTC],
                                     bp[4*OUTC], bp[5*OUTC], bp[6*OUTC], bp[7*OUTC]);
        }
    }

    const int* kin_k  = kin  + (size_t)k * N_PAIRS;
    const int* kout_k = kout + (size_t)k * N_PAIRS;

    const int NCHUNK = N_PAIRS / 16;       // 6250, exact
    const int nwaves = gridDim.x * 4;

    for (int ch = blockIdx.x * 4 + wid; ch < NCHUNK; ch += nwaves) {
        const int e0 = ch * 16;
        const int in_idx = kin_k[e0 + row];
        const int4 oi = *(const int4*)(kout_k + e0 + kg * 4);

        const uint4* xr = xb + (size_t)in_idx * 8;
        const bf16x8 a0 = as_frag(xr[kg]);
        const bf16x8 a1 = as_frag(xr[kg + 4]);

        f32x4 acc[4] = {{0,0,0,0},{0,0,0,0},{0,0,0,0},{0,0,0,0}};
        #pragma unroll
        for (int n = 0; n < 4; ++n) {
            acc[n] = __builtin_amdgcn_mfma_f32_16x16x32_bf16(a0, bfrag[n][0], acc[n], 0, 0, 0);
            acc[n] = __builtin_amdgcn_mfma_f32_16x16x32_bf16(a1, bfrag[n][1], acc[n], 0, 0, 0);
        }

        const int orow[4] = {oi.x, oi.y, oi.z, oi.w};
        #pragma unroll
        for (int j = 0; j < 4; ++j) {
            // Build 4 u64 deltas (one per n) at lanes with row%4==0.
            unsigned long long del[4];
            #pragma unroll
            for (int n = 0; n < 4; ++n) {
                const float v = fminf(fmaxf(acc[n][j], -31.f), 31.f);
                const int d = __float2int_rn(v * QS);
                const int dx = __shfl_xor(d, 1);
                uint32_t pr = ((uint32_t)(uint16_t)d) | (((uint32_t)(uint16_t)dx) << 16);
                const uint32_t pr2 = __shfl_xor((int)pr, 2);
                const int d0 = (int)(short)(pr & 0xFFFFu);
                const int d1 = (int)(short)(pr >> 16);
                const int d2 = (int)(short)(pr2 & 0xFFFFu);
                const int d3 = (int)(short)(pr2 >> 16);
                const int c0 = (d0 < 0) ? 1 : 0;
                const int e1 = d1 - c0;
                const int c1 = (e1 < 0) ? 1 : 0;
                const int e2 = d2 - c1;
                const int c2 = (e2 < 0) ? 1 : 0;
                const int e3 = d3 - c2;
                del[n] = (unsigned long long)(uint16_t)d0
                       | ((unsigned long long)(uint16_t)e1 << 16)
                       | ((unsigned long long)(uint16_t)e2 << 32)
                       | ((unsigned long long)(uint16_t)e3 << 48);
            }
            // Move odd-n deltas to the row&2 lanes so 8 lanes/kg cover a line.
            const unsigned long long m1 = __shfl_xor(del[1], 2);
            const unsigned long long m3 = __shfl_xor(del[3], 2);
            if ((lane & 1) == 0) {
                const int u  = row >> 2;
                const bool hi = (row & 2) != 0;
                unsigned long long* rbase = yq + (size_t)orow[j] * 16;
                const unsigned long long dA = hi ? m1 : del[0];
                const int sA = hi ? (4 + u) : u;            // slots 0..7  (line 0)
                atomicAdd(rbase + sA, dA);
                const unsigned long long dB = hi ? m3 : del[2];
                const int sB = hi ? (12 + u) : (8 + u);     // slots 8..15 (line 1)
                atomicAdd(rbase + sB, dB);
            }
        }
    }
}

// ---------------------------------------------------------------------------
// BN stats from packed accumulator, uint4-vectorized (8 channels/thread/iter).
// ---------------------------------------------------------------------------
__global__ __launch_bounds__(256) void bn_reduce_q(
    const uint4* __restrict__ yq4, float* __restrict__ stats)
{
    __shared__ float ls[128];
    if (threadIdx.x < 128) ls[threadIdx.x] = 0.f;
    __syncthreads();

    const int c8 = threadIdx.x & 7;                 // uint4 slot in row (8/row)
    const int row0 = (blockIdx.x * blockDim.x + threadIdx.x) >> 3;
    const int rstride = (gridDim.x * blockDim.x) >> 3;

    float s0=0,s1=0,s2=0,s3=0,s4=0,s5=0,s6=0,s7=0;
    float q0=0,q1=0,q2=0,q3=0,q4=0,q5=0,q6=0,q7=0;
    for (int r = row0; r < N_VOX; r += rstride) {
        const uint4 v = yq4[(size_t)r * 8 + c8];
        const float f0 = dec_lo(v.x), f1 = dec_hi(v.x);
        const float f2 = dec_lo(v.y), f3 = dec_hi(v.y);
        const float f4 = dec_lo(v.z), f5 = dec_hi(v.z);
        const float f6 = dec_lo(v.w), f7 = dec_hi(v.w);
        s0 += f0; q0 += f0*f0;  s1 += f1; q1 += f1*f1;
        s2 += f2; q2 += f2*f2;  s3 += f3; q3 += f3*f3;
        s4 += f4; q4 += f4*f4;  s5 += f5; q5 += f5*f5;
        s6 += f6; q6 += f6*f6;  s7 += f7; q7 += f7*f7;
    }
    const int ch = c8 * 8;
    atomicAdd(&ls[ch+0], s0);  atomicAdd(&ls[64+ch+0], q0);
    atomicAdd(&ls[ch+1], s1);  atomicAdd(&ls[64+ch+1], q1);
    atomicAdd(&ls[ch+2], s2);  atomicAdd(&ls[64+ch+2], q2);
    atomicAdd(&ls[ch+3], s3);  atomicAdd(&ls[64+ch+3], q3);
    atomicAdd(&ls[ch+4], s4);  atomicAdd(&ls[64+ch+4], q4);
    atomicAdd(&ls[ch+5], s5);  atomicAdd(&ls[64+ch+5], q5);
    atomicAdd(&ls[ch+6], s6);  atomicAdd(&ls[64+ch+6], q6);
    atomicAdd(&ls[ch+7], s7);  atomicAdd(&ls[64+ch+7], q7);
    __syncthreads();
    if (threadIdx.x < 128) atomicAdd(&stats[threadIdx.x], ls[threadIdx.x]);
}

__global__ void bn_finalize(
    const float* __restrict__ stats, const float* __restrict__ gamma,
    const float* __restrict__ beta, float* __restrict__ coef)
{
    const int c = threadIdx.x;
    if (c < 64) {
        const float inv_n = 1.0f / (float)N_VOX;
        const float mean  = stats[c] * inv_n;
        const float var   = stats[64 + c] * inv_n - mean * mean;
        const float scale = gamma[c] * rsqrtf(var + BN_EPS);
        coef[c]      = scale;
        coef[64 + c] = beta[c] - mean * scale;
    }
}

// ---------------------------------------------------------------------------
// Decode + BN + ReLU -> f32 output, uint4-vectorized (8 ch -> 2 float4).
// Overwrites all of d_out (incl. xb).
// ---------------------------------------------------------------------------
__global__ __launch_bounds__(256) void bn_apply_q(
    const uint4* __restrict__ yq4, const float* __restrict__ coef,
    float4* __restrict__ out4)
{
    const size_t total = (size_t)N_VOX * 8;         // uint4 elements
    size_t i = (size_t)blockIdx.x * blockDim.x + threadIdx.x;
    const size_t stride = (size_t)gridDim.x * blockDim.x;   // multiple of 8

    const int ch = (int)(i & 7) * 8;
    const float sc0 = coef[ch+0], sh0 = coef[64+ch+0];
    const float sc1 = coef[ch+1], sh1 = coef[64+ch+1];
    const float sc2 = coef[ch+2], sh2 = coef[64+ch+2];
    const float sc3 = coef[ch+3], sh3 = coef[64+ch+3];
    const float sc4 = coef[ch+4], sh4 = coef[64+ch+4];
    const float sc5 = coef[ch+5], sh5 = coef[64+ch+5];
    const float sc6 = coef[ch+6], sh6 = coef[64+ch+6];
    const float sc7 = coef[ch+7], sh7 = coef[64+ch+7];

    for (; i < total; i += stride) {
        const uint4 v = yq4[i];
        float4 oA, oB;
        oA.x = fmaxf(0.f, fmaf(dec_lo(v.x), sc0, sh0));
        oA.y = fmaxf(0.f, fmaf(dec_hi(v.x), sc1, sh1));
        oA.z = fmaxf(0.f, fmaf(dec_lo(v.y), sc2, sh2));
        oA.w = fmaxf(0.f, fmaf(dec_hi(v.y), sc3, sh3));
        oB.x = fmaxf(0.f, fmaf(dec_lo(v.z), sc4, sh4));
        oB.y = fmaxf(0.f, fmaf(dec_hi(v.z), sc5, sh5));
        oB.z = fmaxf(0.f, fmaf(dec_lo(v.w), sc6, sh6));
        oB.w = fmaxf(0.f, fmaf(dec_hi(v.w), sc7, sh7));
        out4[i * 2]     = oA;
        out4[i * 2 + 1] = oB;
    }
}

// ==================== fallback tier: f32-atomic path into d_out =============
__global__ __launch_bounds__(256) void conv_mfma(
    const float* __restrict__ x, const float* __restrict__ w,
    const int* __restrict__ kin, const int* __restrict__ kout,
    float* __restrict__ y)
{
    const int lane = threadIdx.x & 63;
    const int wid  = threadIdx.x >> 6;
    const int k    = blockIdx.y;
    const int row  = lane & 15;
    const int kg   = lane >> 4;

    const float* wk = w + (size_t)k * (INC * OUTC);

    bf16x8 bfrag[4][2];
    #pragma unroll
    for (int n = 0; n < 4; ++n) {
        #pragma unroll
        for (int kk = 0; kk < 2; ++kk) {
            const int kbase = kk * 32 + kg * 8;
            const float* bp = wk + (size_t)kbase * OUTC + n * 16 + row;
            bfrag[n][kk] = pack_frag(bp[0*OUTC], bp[1*OUTC], bp[2*OUTC], bp[3*OUTC],
                                     bp[4*OUTC], bp[5*OUTC], bp[6*OUTC], bp[7*OUTC]);
        }
    }

    const int* kin_k  = kin  + (size_t)k * N_PAIRS;
    const int* kout_k = kout + (size_t)k * N_PAIRS;

    const int NCHUNK = N_PAIRS / 16;
    const int nwaves = gridDim.x * 4;

    for (int ch = blockIdx.x * 4 + wid; ch < NCHUNK; ch += nwaves) {
        const int e0 = ch * 16;
        const int in_idx = kin_k[e0 + row];
        const int4 oi = *(const int4*)(kout_k + e0 + kg * 4);

        const float* xr = x + (size_t)in_idx * INC + kg * 8;
        bf16x8 afrag[2];
        #pragma unroll
        for (int kk = 0; kk < 2; ++kk) {
            const f32x4 a0 = *(const f32x4*)(xr + kk * 32);
            const f32x4 a1 = *(const f32x4*)(xr + kk * 32 + 4);
            afrag[kk] = pack_frag(a0.x, a0.y, a0.z, a0.w, a1.x, a1.y, a1.z, a1.w);
        }

        f32x4 acc[4] = {{0,0,0,0},{0,0,0,0},{0,0,0,0},{0,0,0,0}};
        #pragma unroll
        for (int n = 0; n < 4; ++n) {
            acc[n] = __builtin_amdgcn_mfma_f32_16x16x32_bf16(afrag[0], bfrag[n][0], acc[n], 0, 0, 0);
            acc[n] = __builtin_amdgcn_mfma_f32_16x16x32_bf16(afrag[1], bfrag[n][1], acc[n], 0, 0, 0);
        }

        const int orow[4] = {oi.x, oi.y, oi.z, oi.w};
        #pragma unroll
        for (int j = 0; j < 4; ++j) {
            float* base = y + (size_t)orow[j] * OUTC + row;
            unsafeAtomicAdd(base + 0,  acc[0][j]);
            unsafeAtomicAdd(base + 16, acc[1][j]);
            unsafeAtomicAdd(base + 32, acc[2][j]);
            unsafeAtomicAdd(base + 48, acc[3][j]);
        }
    }
}

__global__ __launch_bounds__(256) void bn_reduce(
    const float* __restrict__ y, float* __restrict__ stats)
{
    __shared__ float s_sum[256];
    __shared__ float s_sq[256];

    const int c = threadIdx.x & 63;
    const int row0 = (blockIdx.x * blockDim.x + threadIdx.x) >> 6;
    const int rstride = (gridDim.x * blockDim.x) >> 6;

    float s = 0.f, ss = 0.f;
    for (int r = row0; r < N_VOX; r += rstride) {
        const float v = y[(size_t)r * OUTC + c];
        s += v;
        ss += v * v;
    }
    s_sum[threadIdx.x] = s;
    s_sq[threadIdx.x]  = ss;
    __syncthreads();

    if (threadIdx.x < 64) {
        const float ts  = (s_sum[c] + s_sum[64 + c]) + (s_sum[128 + c] + s_sum[192 + c]);
        const float tss = (s_sq[c]  + s_sq[64 + c])  + (s_sq[128 + c]  + s_sq[192 + c]);
        atomicAdd(&stats[c], ts);
        atomicAdd(&stats[64 + c], tss);
    }
}

__global__ __launch_bounds__(256) void bn_apply(
    float* __restrict__ y, const float* __restrict__ coef)
{
    const size_t total4 = (size_t)N_VOX * OUTC / 4;
    size_t i = (size_t)blockIdx.x * blockDim.x + threadIdx.x;
    const size_t stride = (size_t)gridDim.x * blockDim.x;

    const int c0 = (int)((i * 4) & 63);
    const float sc0 = coef[c0 + 0], sh0 = coef[64 + c0 + 0];
    const float sc1 = coef[c0 + 1], sh1 = coef[64 + c0 + 1];
    const float sc2 = coef[c0 + 2], sh2 = coef[64 + c0 + 2];
    const float sc3 = coef[c0 + 3], sh3 = coef[64 + c0 + 3];

    float4* y4 = (float4*)y;
    for (; i < total4; i += stride) {
        float4 v = y4[i];
        v.x = fmaxf(0.f, fmaf(v.x, sc0, sh0));
        v.y = fmaxf(0.f, fmaf(v.y, sc1, sh1));
        v.z = fmaxf(0.f, fmaf(v.z, sc2, sh2));
        v.w = fmaxf(0.f, fmaf(v.w, sc3, sh3));
        y4[i] = v;
    }
}

extern "C" void kernel_launch(void* const* d_in, const int* in_sizes, int n_in,
                              void* d_out, int out_size, void* d_ws, size_t ws_size,
                              hipStream_t stream)
{
    const float* x     = (const float*)d_in[0];
    const float* w     = (const float*)d_in[1];
    const float* gamma = (const float*)d_in[2];
    const float* beta  = (const float*)d_in[3];
    const int*   kin   = (const int*)d_in[4];
    const int*   kout  = (const int*)d_in[5];

    const size_t yq_bytes = (size_t)N_VOX * 16 * 8;   // 25.6 MB
    const size_t needA = yq_bytes + 1024;

    if (ws_size >= needA) {
        unsigned long long* yq = (unsigned long long*)d_ws;
        float* stats = (float*)((char*)d_ws + yq_bytes);
        float* coef  = stats + 128;
        uint4* xb    = (uint4*)d_out;                 // bf16 x inside d_out

        hipMemsetAsync(yq, 0, yq_bytes, stream);
        hipMemsetAsync(stats, 0, 128 * sizeof(float), stream);
        xcast<<<2048, 256, 0, stream>>>(x, xb);
        conv_q<<<dim3(192, KK), 256, 0, stream>>>(xb, w, kin, kout, yq);
        bn_reduce_q<<<512, 256, 0, stream>>>((const uint4*)yq, stats);
        bn_finalize<<<1, 64, 0, stream>>>(stats, gamma, beta, coef);
        bn_apply_q<<<2048, 256, 0, stream>>>((const uint4*)yq, coef, (float4*)d_out);
    } else {
        // f32-atomic fallback (proven): y lives in d_out
        float* y     = (float*)d_out;
        float* stats = (float*)d_ws;
        float* coef  = stats + 128;

        hipMemsetAsync(y, 0, (size_t)N_VOX * OUTC * sizeof(float), stream);
        hipMemsetAsync(stats, 0, 128 * sizeof(float), stream);

        conv_mfma<<<dim3(64, KK), 256, 0, stream>>>(x, w, kin, kout, y);
        bn_reduce<<<512, 256, 0, stream>>>(y, stats);
        bn_finalize<<<1, 64, 0, stream>>>(stats, gamma, beta, coef);
        bn_apply<<<2048, 256, 0, stream>>>(y, coef);
    }
}